// Round 1
// baseline (4283.822 us; speedup 1.0000x reference)
//
#include <hip/hip_runtime.h>

#define N_NODES 100000
#define N_EDGES 800000
#define NREL 3
#define F 128  // feature width at every stage

__device__ __forceinline__ int f2o(float f) {
    int i = __float_as_int(f);
    return i >= 0 ? i : i ^ 0x7fffffff;  // order-preserving map f32 -> int
}
__device__ __forceinline__ float o2f(int i) {
    return __int_as_float(i >= 0 ? i : i ^ 0x7fffffff);
}
__device__ __forceinline__ float lrelu(float v) { return v >= 0.f ? v : 0.2f * v; }

// ---------------- GEMM: Y[n,j] = sum_k X[n,k] * W[k,j]; X:[nrows,128] W:[128,128]
__global__ __launch_bounds__(256) void gemm128_kernel(const float* __restrict__ X,
                                                      const float* __restrict__ W,
                                                      float* __restrict__ Y, int nrows) {
    __shared__ __align__(16) float xs[128 * 132];  // transposed: xs[k*132 + r]
    __shared__ __align__(16) float ws[128 * 128];  // ws[k*128 + j]
    const int t = threadIdx.x;
    const int row0 = blockIdx.x * 128;
    for (int i = t; i < 128 * 128; i += 256) {
        ws[i] = W[i];
        int k = i & 127, r = i >> 7;
        int gr = row0 + r;
        xs[k * 132 + r] = (gr < nrows) ? X[(size_t)gr * 128 + k] : 0.f;
    }
    __syncthreads();
    const int s = t & 15;   // col slot: cols {s*4+j, 64+s*4+j}
    const int p = t >> 4;   // row slot: rows {p*4+i, 64+p*4+i}
    float acc[8][8];
#pragma unroll
    for (int i = 0; i < 8; ++i)
#pragma unroll
        for (int j = 0; j < 8; ++j) acc[i][j] = 0.f;

    for (int k = 0; k < 128; ++k) {
        const float4 xa = *(const float4*)&xs[k * 132 + p * 4];
        const float4 xb = *(const float4*)&xs[k * 132 + 64 + p * 4];
        const float4 wa = *(const float4*)&ws[k * 128 + s * 4];
        const float4 wb = *(const float4*)&ws[k * 128 + 64 + s * 4];
        float xr[8] = {xa.x, xa.y, xa.z, xa.w, xb.x, xb.y, xb.z, xb.w};
        float wc[8] = {wa.x, wa.y, wa.z, wa.w, wb.x, wb.y, wb.z, wb.w};
#pragma unroll
        for (int i = 0; i < 8; ++i)
#pragma unroll
            for (int j = 0; j < 8; ++j) acc[i][j] += xr[i] * wc[j];
    }
#pragma unroll
    for (int i = 0; i < 8; ++i) {
        int gr = row0 + (i >> 2) * 64 + p * 4 + (i & 3);
        if (gr < nrows) {
            float4 v0 = make_float4(acc[i][0], acc[i][1], acc[i][2], acc[i][3]);
            float4 v1 = make_float4(acc[i][4], acc[i][5], acc[i][6], acc[i][7]);
            *(float4*)&Y[(size_t)gr * 128 + s * 4] = v0;
            *(float4*)&Y[(size_t)gr * 128 + 64 + s * 4] = v1;
        }
    }
}

// ---------------- el/er: el[n,h] = sum_d feat[n,h,d]*al[h,d]
template <int H, int D>
__global__ __launch_bounds__(256) void el_er_kernel(const float* __restrict__ feat,
                                                    const float* __restrict__ al,
                                                    const float* __restrict__ ar,
                                                    float* __restrict__ el,
                                                    float* __restrict__ er) {
    int idx = blockIdx.x * 256 + threadIdx.x;  // idx = n*H + h
    if (idx >= N_NODES * H) return;
    int h = idx & (H - 1);
    const float4* fp = (const float4*)(feat + (size_t)idx * D);
    const float4* ap = (const float4*)(al + h * D);
    const float4* bp = (const float4*)(ar + h * D);
    float sl = 0.f, sr = 0.f;
#pragma unroll
    for (int q = 0; q < D / 4; ++q) {
        float4 f = fp[q], a = ap[q], b = bp[q];
        sl += f.x * a.x + f.y * a.y + f.z * a.z + f.w * a.w;
        sr += f.x * b.x + f.y * b.y + f.z * b.z + f.w * b.w;
    }
    el[idx] = sl;
    er[idx] = sr;
}

__global__ __launch_bounds__(256) void init_md_kernel(int* __restrict__ m_i,
                                                      float* __restrict__ denom, int count) {
    int i = blockIdx.x * 256 + threadIdx.x;
    if (i < count) {
        m_i[i] = (int)0x80000000;  // < f2o(any float)
        denom[i] = 0.f;
    }
}

template <int H>
__global__ __launch_bounds__(256) void edge_max_kernel(const int* __restrict__ src,
                                                       const int* __restrict__ dst,
                                                       const float* __restrict__ el,
                                                       const float* __restrict__ er,
                                                       int* __restrict__ m_i) {
    int e = blockIdx.x * 256 + threadIdx.x;
    if (e >= N_EDGES) return;
    int s = src[e], d = dst[e];
#pragma unroll
    for (int h = 0; h < H; ++h) {
        float v = lrelu(el[s * H + h] + er[d * H + h]);
        atomicMax(&m_i[d * H + h], f2o(v));
    }
}

template <int H>
__global__ __launch_bounds__(256) void edge_sum_kernel(const int* __restrict__ src,
                                                       const int* __restrict__ dst,
                                                       const float* __restrict__ el,
                                                       const float* __restrict__ er,
                                                       const int* __restrict__ m_i,
                                                       float* __restrict__ denom) {
    int e = blockIdx.x * 256 + threadIdx.x;
    if (e >= N_EDGES) return;
    int s = src[e], d = dst[e];
#pragma unroll
    for (int h = 0; h < H; ++h) {
        float v = lrelu(el[s * H + h] + er[d * H + h]);
        float ex = __expf(v - o2f(m_i[d * H + h]));
        atomicAdd(&denom[d * H + h], ex);
    }
}

// one 64-lane wave per edge; lane covers features {lane, lane+64}
template <int H, int D>
__global__ __launch_bounds__(256) void edge_aggr_kernel(const int* __restrict__ src,
                                                        const int* __restrict__ dst,
                                                        const float* __restrict__ el,
                                                        const float* __restrict__ er,
                                                        const int* __restrict__ m_i,
                                                        const float* __restrict__ denom,
                                                        const float* __restrict__ feat,
                                                        float* __restrict__ acc) {
    long long gid = (long long)blockIdx.x * 256 + threadIdx.x;
    int e = (int)(gid >> 6);
    int lane = (int)(gid & 63);
    if (e >= N_EDGES) return;
    int s = src[e], d = dst[e];
#pragma unroll
    for (int t2 = 0; t2 < 2; ++t2) {
        int f = lane + 64 * t2;
        int h = f / D;  // compile-time D
        float v = lrelu(el[s * H + h] + er[d * H + h]);
        float a = __expf(v - o2f(m_i[d * H + h])) / fmaxf(denom[d * H + h], 1e-9f);
        atomicAdd(&acc[(size_t)d * F + f], a * feat[(size_t)s * F + f]);
    }
}

// h1 = elu(acc/3 + x + mean_bias); in place into acc
__global__ __launch_bounds__(256) void finalize1_kernel(float* __restrict__ acc,
                                                        const float* __restrict__ x,
                                                        const float* __restrict__ b1) {
    size_t i = (size_t)blockIdx.x * 256 + threadIdx.x;
    if (i >= (size_t)N_NODES * F) return;
    int f = (int)(i & 127);
    float bsum = (b1[f] + b1[F + f] + b1[2 * F + f]) * (1.f / 3.f);
    float v = acc[i] * (1.f / 3.f) + x[i] + bsum;
    acc[i] = v > 0.f ? v : (__expf(v) - 1.f);
}

// out = out/3 + h1 + mean_bias
__global__ __launch_bounds__(256) void finalize2_kernel(float* __restrict__ out,
                                                        const float* __restrict__ h1,
                                                        const float* __restrict__ b2) {
    size_t i = (size_t)blockIdx.x * 256 + threadIdx.x;
    if (i >= (size_t)N_NODES * F) return;
    int f = (int)(i & 127);
    float bsum = (b2[f] + b2[F + f] + b2[2 * F + f]) * (1.f / 3.f);
    out[i] = out[i] * (1.f / 3.f) + h1[i] + bsum;
}

extern "C" void kernel_launch(void* const* d_in, const int* in_sizes, int n_in,
                              void* d_out, int out_size, void* d_ws, size_t ws_size,
                              hipStream_t stream) {
    const float* x   = (const float*)d_in[0];
    const int* esrc  = (const int*)d_in[1];
    const int* edst  = (const int*)d_in[2];
    const float* W1  = (const float*)d_in[3];
    const float* b1  = (const float*)d_in[4];
    const float* al1 = (const float*)d_in[5];
    const float* ar1 = (const float*)d_in[6];
    const float* W2  = (const float*)d_in[7];
    const float* b2  = (const float*)d_in[8];
    const float* al2 = (const float*)d_in[9];
    const float* ar2 = (const float*)d_in[10];
    float* out = (float*)d_out;

    float* feat  = (float*)d_ws;                       // [N,128]
    float* acc   = feat + (size_t)N_NODES * F;         // [N,128]; becomes h1
    float* el    = acc + (size_t)N_NODES * F;          // [N,4]
    float* er    = el + (size_t)N_NODES * 4;           // [N,4]
    int*   m_i   = (int*)(er + (size_t)N_NODES * 4);   // [N,4]
    float* denom = (float*)(m_i + (size_t)N_NODES * 4);// [N,4]

    dim3 b256(256);
    const int gemm_grid = (N_NODES + 127) / 128;
    const int eg = (N_EDGES + 255) / 256;
    const int ag = (int)(((size_t)N_EDGES * 64 + 255) / 256);
    const int ng4 = (N_NODES * 4 + 255) / 256;
    const int ng1 = (N_NODES + 255) / 256;
    const int fg = (int)(((size_t)N_NODES * F + 255) / 256);

    hipMemsetAsync(acc, 0, (size_t)N_NODES * F * sizeof(float), stream);

    // ---- layer 1: GATConv(128 -> 32, 4 heads) per relation, mean
    for (int r = 0; r < NREL; ++r) {
        gemm128_kernel<<<gemm_grid, b256, 0, stream>>>(x, W1 + (size_t)r * F * F, feat, N_NODES);
        el_er_kernel<4, 32><<<ng4, b256, 0, stream>>>(feat, al1 + r * F, ar1 + r * F, el, er);
        init_md_kernel<<<ng4, b256, 0, stream>>>(m_i, denom, N_NODES * 4);
        edge_max_kernel<4><<<eg, b256, 0, stream>>>(esrc + (size_t)r * N_EDGES, edst + (size_t)r * N_EDGES, el, er, m_i);
        edge_sum_kernel<4><<<eg, b256, 0, stream>>>(esrc + (size_t)r * N_EDGES, edst + (size_t)r * N_EDGES, el, er, m_i, denom);
        edge_aggr_kernel<4, 32><<<ag, b256, 0, stream>>>(esrc + (size_t)r * N_EDGES, edst + (size_t)r * N_EDGES,
                                                         el, er, m_i, denom, feat, acc);
    }
    finalize1_kernel<<<fg, b256, 0, stream>>>(acc, x, b1);  // acc := h1

    // ---- layer 2: GATConv(128 -> 128, 1 head) per relation, mean
    hipMemsetAsync(out, 0, (size_t)N_NODES * F * sizeof(float), stream);
    for (int r = 0; r < NREL; ++r) {
        gemm128_kernel<<<gemm_grid, b256, 0, stream>>>(acc, W2 + (size_t)r * F * F, feat, N_NODES);
        el_er_kernel<1, 128><<<ng1, b256, 0, stream>>>(feat, al2 + r * F, ar2 + r * F, el, er);
        init_md_kernel<<<ng1, b256, 0, stream>>>(m_i, denom, N_NODES);
        edge_max_kernel<1><<<eg, b256, 0, stream>>>(esrc + (size_t)r * N_EDGES, edst + (size_t)r * N_EDGES, el, er, m_i);
        edge_sum_kernel<1><<<eg, b256, 0, stream>>>(esrc + (size_t)r * N_EDGES, edst + (size_t)r * N_EDGES, el, er, m_i, denom);
        edge_aggr_kernel<1, 128><<<ag, b256, 0, stream>>>(esrc + (size_t)r * N_EDGES, edst + (size_t)r * N_EDGES,
                                                          el, er, m_i, denom, feat, out);
    }
    finalize2_kernel<<<fg, b256, 0, stream>>>(out, acc, b2);
}

// Round 3
// 2053.914 us; speedup vs baseline: 2.0857x; 2.0857x over previous
//
#include <hip/hip_runtime.h>
#include <hip/hip_bf16.h>

#define NN 100000
#define NE 800000
#define NR 3
#define F 128
#define M3 (NR * NN)               // 300000 rows of CSR across relations
#define E3 (NR * NE)               // 2400000 edges total
#define NB1 ((M3 + 255) / 256)     // scan blocks

__device__ __forceinline__ float lrelu(float v) { return v >= 0.f ? v : 0.2f * v; }
__device__ __forceinline__ float bf2f(unsigned short u) {
    return __uint_as_float(((unsigned)u) << 16);
}
__device__ __forceinline__ unsigned short f2bf(float f) {
    __hip_bfloat16 h = __float2bfloat16(f);
    unsigned short u;
    __builtin_memcpy(&u, &h, 2);
    return u;
}

// ---------------- CSR build ----------------
__global__ __launch_bounds__(256) void hist_kernel(const int* __restrict__ edst,
                                                   int* __restrict__ counts) {
    int i = blockIdx.x * 256 + threadIdx.x;
    if (i >= E3) return;
    int r = i / NE;
    atomicAdd(&counts[r * NN + edst[i]], 1);
}

// block-wise exclusive scan (in-place), block sums out
__global__ __launch_bounds__(256) void scan1_kernel(int* __restrict__ data,
                                                    int* __restrict__ bsum, int n) {
    __shared__ int lds[256];
    int i = blockIdx.x * 256 + threadIdx.x;
    int v = (i < n) ? data[i] : 0;
    lds[threadIdx.x] = v;
    __syncthreads();
#pragma unroll
    for (int off = 1; off < 256; off <<= 1) {
        int t = (threadIdx.x >= off) ? lds[threadIdx.x - off] : 0;
        __syncthreads();
        lds[threadIdx.x] += t;
        __syncthreads();
    }
    int incl = lds[threadIdx.x];
    if (i < n) data[i] = incl - v;
    if (threadIdx.x == 255) bsum[blockIdx.x] = incl;
}

// single-block scan of block sums (exclusive, in place)
__global__ __launch_bounds__(256) void scan2_kernel(int* __restrict__ bsum, int nb) {
    __shared__ int lds[256];
    int carry = 0;
    for (int base = 0; base < nb; base += 256) {
        int i = base + threadIdx.x;
        int v = (i < nb) ? bsum[i] : 0;
        lds[threadIdx.x] = v;
        __syncthreads();
#pragma unroll
        for (int off = 1; off < 256; off <<= 1) {
            int t = (threadIdx.x >= off) ? lds[threadIdx.x - off] : 0;
            __syncthreads();
            lds[threadIdx.x] += t;
            __syncthreads();
        }
        if (i < nb) bsum[i] = (lds[threadIdx.x] - v) + carry;
        int tot = lds[255];
        __syncthreads();
        carry += tot;
    }
}

__global__ __launch_bounds__(256) void scan3_kernel(int* __restrict__ row_ptr,
                                                    int* __restrict__ alloc,
                                                    const int* __restrict__ bsum, int n) {
    int i = blockIdx.x * 256 + threadIdx.x;
    if (i >= n) return;
    int v = row_ptr[i] + bsum[blockIdx.x];
    row_ptr[i] = v;
    alloc[i] = v;
}

__global__ __launch_bounds__(256) void scatter_kernel(const int* __restrict__ esrc,
                                                      const int* __restrict__ edst,
                                                      int* __restrict__ alloc,
                                                      int* __restrict__ csr_src) {
    int i = blockIdx.x * 256 + threadIdx.x;
    if (i >= E3) return;
    int r = i / NE;
    int d = edst[i];
    int pos = atomicAdd(&alloc[r * NN + d], 1);
    csr_src[pos] = esrc[i];
}

// ---------------- GEMM: Y[n,j](bf16) = sum_k X[n,k] * W[k,j]; X:[NN,128] W:[128,128]
__global__ __launch_bounds__(256) void gemm128_kernel(const float* __restrict__ X,
                                                      const float* __restrict__ W,
                                                      unsigned short* __restrict__ Y) {
    __shared__ __align__(16) float xs[128 * 132];  // transposed: xs[k*132 + r]
    __shared__ __align__(16) float ws[128 * 128];  // ws[k*128 + j]
    const int t = threadIdx.x;
    const int row0 = blockIdx.x * 128;
    for (int i = t; i < 128 * 128; i += 256) {
        ws[i] = W[i];
        int k = i & 127, r = i >> 7;
        int gr = row0 + r;
        xs[k * 132 + r] = (gr < NN) ? X[(size_t)gr * 128 + k] : 0.f;
    }
    __syncthreads();
    const int s = t & 15;
    const int p = t >> 4;
    float acc[8][8];
#pragma unroll
    for (int i = 0; i < 8; ++i)
#pragma unroll
        for (int j = 0; j < 8; ++j) acc[i][j] = 0.f;

    for (int k = 0; k < 128; ++k) {
        const float4 xa = *(const float4*)&xs[k * 132 + p * 4];
        const float4 xb = *(const float4*)&xs[k * 132 + 64 + p * 4];
        const float4 wa = *(const float4*)&ws[k * 128 + s * 4];
        const float4 wb = *(const float4*)&ws[k * 128 + 64 + s * 4];
        float xr[8] = {xa.x, xa.y, xa.z, xa.w, xb.x, xb.y, xb.z, xb.w};
        float wc[8] = {wa.x, wa.y, wa.z, wa.w, wb.x, wb.y, wb.z, wb.w};
#pragma unroll
        for (int i = 0; i < 8; ++i)
#pragma unroll
            for (int j = 0; j < 8; ++j) acc[i][j] += xr[i] * wc[j];
    }
#pragma unroll
    for (int i = 0; i < 8; ++i) {
        int gr = row0 + (i >> 2) * 64 + p * 4 + (i & 3);
        if (gr < NN) {
            ushort4 v0, v1;
            v0.x = f2bf(acc[i][0]); v0.y = f2bf(acc[i][1]);
            v0.z = f2bf(acc[i][2]); v0.w = f2bf(acc[i][3]);
            v1.x = f2bf(acc[i][4]); v1.y = f2bf(acc[i][5]);
            v1.z = f2bf(acc[i][6]); v1.w = f2bf(acc[i][7]);
            *(ushort4*)&Y[(size_t)gr * 128 + s * 4] = v0;
            *(ushort4*)&Y[(size_t)gr * 128 + 64 + s * 4] = v1;
        }
    }
}

// ---------------- el/er from bf16 feat
template <int H, int D>
__global__ __launch_bounds__(256) void el_er_kernel(const unsigned short* __restrict__ featb,
                                                    const float* __restrict__ al,
                                                    const float* __restrict__ ar,
                                                    float* __restrict__ el,
                                                    float* __restrict__ er) {
    int idx = blockIdx.x * 256 + threadIdx.x;  // idx = n*H + h
    if (idx >= NN * H) return;
    int h = idx & (H - 1);
    const uint4* fp = (const uint4*)(featb + (size_t)idx * D);
    const float4* ap = (const float4*)(al + h * D);
    const float4* bp = (const float4*)(ar + h * D);
    float sl = 0.f, sr = 0.f;
#pragma unroll
    for (int q = 0; q < D / 8; ++q) {
        uint4 u = fp[q];
        float f[8] = {bf2f((unsigned short)(u.x & 0xffff)), bf2f((unsigned short)(u.x >> 16)),
                      bf2f((unsigned short)(u.y & 0xffff)), bf2f((unsigned short)(u.y >> 16)),
                      bf2f((unsigned short)(u.z & 0xffff)), bf2f((unsigned short)(u.z >> 16)),
                      bf2f((unsigned short)(u.w & 0xffff)), bf2f((unsigned short)(u.w >> 16))};
        float4 a0 = ap[2 * q], a1 = ap[2 * q + 1];
        float4 b0 = bp[2 * q], b1 = bp[2 * q + 1];
        sl += f[0] * a0.x + f[1] * a0.y + f[2] * a0.z + f[3] * a0.w +
              f[4] * a1.x + f[5] * a1.y + f[6] * a1.z + f[7] * a1.w;
        sr += f[0] * b0.x + f[1] * b0.y + f[2] * b0.z + f[3] * b0.w +
              f[4] * b1.x + f[5] * b1.y + f[6] * b1.z + f[7] * b1.w;
    }
    el[idx] = sl;
    er[idx] = sr;
}

// ---------------- per-(dst,head) online softmax stats
template <int H>
__global__ __launch_bounds__(256) void stats_kernel(const int* __restrict__ row_ptr,
                                                    const int* __restrict__ csr_src,
                                                    const float* __restrict__ el,
                                                    const float* __restrict__ er,
                                                    float* __restrict__ mbuf,
                                                    float* __restrict__ dbuf, int rbase) {
    int t = blockIdx.x * 256 + threadIdx.x;  // t = d*H + h
    if (t >= NN * H) return;
    int d = t / H, h = t - (t / H) * H;
    int idx = rbase + d;
    int rs = row_ptr[idx];
    int re = (idx + 1 < M3) ? row_ptr[idx + 1] : E3;
    float erv = er[t];
    float m = -INFINITY, sum = 0.f;
    for (int i = rs; i < re; ++i) {
        int s = csr_src[i];
        float v = lrelu(el[s * H + h] + erv);
        float mn = fmaxf(m, v);
        sum = sum * __expf(m - mn) + __expf(v - mn);
        m = mn;
    }
    mbuf[t] = m;
    dbuf[t] = sum;
}

// ---------------- aggregation: one 64-lane wave per dst, lane covers f, f+64
template <int H, int ACCUM>
__global__ __launch_bounds__(256) void aggr_kernel(const int* __restrict__ row_ptr,
                                                   const int* __restrict__ csr_src,
                                                   const float* __restrict__ el,
                                                   const float* __restrict__ er,
                                                   const float* __restrict__ mbuf,
                                                   const float* __restrict__ dbuf,
                                                   const unsigned short* __restrict__ featb,
                                                   float* __restrict__ acc, int rbase) {
    const int gid = blockIdx.x * 256 + threadIdx.x;
    const int d = gid >> 6;
    const int lane = gid & 63;
    if (d >= NN) return;
    const int idx = rbase + d;
    const int rs = row_ptr[idx];
    const int re = (idx + 1 < M3) ? row_ptr[idx + 1] : E3;
    const int f0 = lane, f1 = lane + 64;
    const int D = F / H;
    const int h0 = f0 / D, h1 = f1 / D;
    const float er0 = er[d * H + h0], er1 = er[d * H + h1];
    const float m0 = mbuf[d * H + h0], m1 = mbuf[d * H + h1];
    const float rd0 = 1.f / fmaxf(dbuf[d * H + h0], 1e-9f);
    const float rd1 = 1.f / fmaxf(dbuf[d * H + h1], 1e-9f);
    float a0 = 0.f, a1 = 0.f;
    for (int i = rs; i < re; ++i) {
        int s = csr_src[i];
        const unsigned short* fr = featb + (size_t)s * F;
        float v0 = lrelu(el[s * H + h0] + er0);
        float v1 = lrelu(el[s * H + h1] + er1);
        a0 += __expf(v0 - m0) * rd0 * bf2f(fr[f0]);
        a1 += __expf(v1 - m1) * rd1 * bf2f(fr[f1]);
    }
    size_t o = (size_t)d * F;
    if (ACCUM) {
        acc[o + f0] += a0;
        acc[o + f1] += a1;
    } else {
        acc[o + f0] = a0;
        acc[o + f1] = a1;
    }
}

// h1 = elu(acc/3 + x + mean_bias), in place
__global__ __launch_bounds__(256) void finalize1_kernel(float* __restrict__ acc,
                                                        const float* __restrict__ x,
                                                        const float* __restrict__ b1) {
    size_t i = (size_t)blockIdx.x * 256 + threadIdx.x;
    if (i >= (size_t)NN * F) return;
    int f = (int)(i & 127);
    float bsum = (b1[f] + b1[F + f] + b1[2 * F + f]) * (1.f / 3.f);
    float v = acc[i] * (1.f / 3.f) + x[i] + bsum;
    acc[i] = v > 0.f ? v : (__expf(v) - 1.f);
}

// out = out/3 + h1 + mean_bias
__global__ __launch_bounds__(256) void finalize2_kernel(float* __restrict__ out,
                                                        const float* __restrict__ h1,
                                                        const float* __restrict__ b2) {
    size_t i = (size_t)blockIdx.x * 256 + threadIdx.x;
    if (i >= (size_t)NN * F) return;
    int f = (int)(i & 127);
    float bsum = (b2[f] + b2[F + f] + b2[2 * F + f]) * (1.f / 3.f);
    out[i] = out[i] * (1.f / 3.f) + h1[i] + bsum;
}

extern "C" void kernel_launch(void* const* d_in, const int* in_sizes, int n_in,
                              void* d_out, int out_size, void* d_ws, size_t ws_size,
                              hipStream_t stream) {
    const float* x   = (const float*)d_in[0];
    const int* esrc  = (const int*)d_in[1];
    const int* edst  = (const int*)d_in[2];
    const float* W1  = (const float*)d_in[3];
    const float* b1  = (const float*)d_in[4];
    const float* al1 = (const float*)d_in[5];
    const float* ar1 = (const float*)d_in[6];
    const float* W2  = (const float*)d_in[7];
    const float* b2  = (const float*)d_in[8];
    const float* al2 = (const float*)d_in[9];
    const float* ar2 = (const float*)d_in[10];
    float* out = (float*)d_out;

    // workspace layout
    char* p = (char*)d_ws;
    unsigned short* featb = (unsigned short*)p;         p += (size_t)NN * F * 2;       // 25.6 MB
    float* acc   = (float*)p;                           p += (size_t)NN * F * 4;       // 51.2 MB
    float* el    = (float*)p;                           p += (size_t)NN * 4 * 4;
    float* er    = (float*)p;                           p += (size_t)NN * 4 * 4;
    float* mbuf  = (float*)p;                           p += (size_t)NN * 4 * 4;
    float* dbuf  = (float*)p;                           p += (size_t)NN * 4 * 4;
    int* row_ptr = (int*)p;                             p += (size_t)M3 * 4;
    int* alloc   = (int*)p;                             p += (size_t)M3 * 4;
    int* bsum    = (int*)p;                             p += (size_t)((NB1 + 63) & ~63) * 4;
    int* csr_src = (int*)p;                             p += (size_t)E3 * 4;

    dim3 b256(256);
    const int eg3 = (E3 + 255) / 256;
    const int gemm_grid = (NN + 127) / 128;
    const int ng4 = (NN * 4 + 255) / 256;
    const int ng1 = (NN + 255) / 256;
    const int agg = (NN * 64 + 255) / 256;
    const int fg = (int)(((size_t)NN * F + 255) / 256);

    // ---- build CSR by dst (shared by both layers)
    hipMemsetAsync(row_ptr, 0, (size_t)M3 * 4, stream);
    hist_kernel<<<eg3, b256, 0, stream>>>(edst, row_ptr);
    scan1_kernel<<<NB1, b256, 0, stream>>>(row_ptr, bsum, M3);
    scan2_kernel<<<1, b256, 0, stream>>>(bsum, NB1);
    scan3_kernel<<<NB1, b256, 0, stream>>>(row_ptr, alloc, bsum, M3);
    scatter_kernel<<<eg3, b256, 0, stream>>>(esrc, edst, alloc, csr_src);

    // ---- layer 1: GATConv(128 -> 32, 4 heads) per relation, mean
    for (int r = 0; r < NR; ++r) {
        int rbase = r * NN;
        gemm128_kernel<<<gemm_grid, b256, 0, stream>>>(x, W1 + (size_t)r * F * F, featb);
        el_er_kernel<4, 32><<<ng4, b256, 0, stream>>>(featb, al1 + r * F, ar1 + r * F, el, er);
        stats_kernel<4><<<ng4, b256, 0, stream>>>(row_ptr, csr_src, el, er, mbuf, dbuf, rbase);
        if (r == 0)
            aggr_kernel<4, 0><<<agg, b256, 0, stream>>>(row_ptr, csr_src, el, er, mbuf, dbuf, featb, acc, rbase);
        else
            aggr_kernel<4, 1><<<agg, b256, 0, stream>>>(row_ptr, csr_src, el, er, mbuf, dbuf, featb, acc, rbase);
    }
    finalize1_kernel<<<fg, b256, 0, stream>>>(acc, x, b1);  // acc := h1

    // ---- layer 2: GATConv(128 -> 128, 1 head) per relation, mean
    for (int r = 0; r < NR; ++r) {
        int rbase = r * NN;
        gemm128_kernel<<<gemm_grid, b256, 0, stream>>>(acc, W2 + (size_t)r * F * F, featb);
        el_er_kernel<1, 128><<<ng1, b256, 0, stream>>>(featb, al2 + r * F, ar2 + r * F, el, er);
        stats_kernel<1><<<ng1, b256, 0, stream>>>(row_ptr, csr_src, el, er, mbuf, dbuf, rbase);
        if (r == 0)
            aggr_kernel<1, 0><<<agg, b256, 0, stream>>>(row_ptr, csr_src, el, er, mbuf, dbuf, featb, out, rbase);
        else
            aggr_kernel<1, 1><<<agg, b256, 0, stream>>>(row_ptr, csr_src, el, er, mbuf, dbuf, featb, out, rbase);
    }
    finalize2_kernel<<<fg, b256, 0, stream>>>(out, acc, b2);
}

// Round 4
// 1220.716 us; speedup vs baseline: 3.5093x; 1.6825x over previous
//
#include <hip/hip_runtime.h>
#include <hip/hip_bf16.h>

#define NN 100000
#define NE 800000
#define NR 3
#define F 128
#define M3 (NR * NN)               // 300000 rows of CSR across relations
#define E3 (NR * NE)               // 2400000 edges total
#define NB1 ((M3 + 255) / 256)     // scan blocks

typedef __bf16 bf16x8 __attribute__((ext_vector_type(8)));
typedef float f32x4 __attribute__((ext_vector_type(4)));

__device__ __forceinline__ float lrelu(float v) { return v >= 0.f ? v : 0.2f * v; }
__device__ __forceinline__ float bf2f(unsigned short u) {
    return __uint_as_float(((unsigned)u) << 16);
}
__device__ __forceinline__ unsigned short f2bf(float f) {
    __hip_bfloat16 h = __float2bfloat16(f);
    unsigned short u;
    __builtin_memcpy(&u, &h, 2);
    return u;
}

// ---------------- CSR build ----------------
__global__ __launch_bounds__(256) void hist_kernel(const int* __restrict__ edst,
                                                   int* __restrict__ counts) {
    int i = blockIdx.x * 256 + threadIdx.x;
    if (i >= E3) return;
    int r = i / NE;
    atomicAdd(&counts[r * NN + edst[i]], 1);
}

__global__ __launch_bounds__(256) void scan1_kernel(int* __restrict__ data,
                                                    int* __restrict__ bsum, int n) {
    __shared__ int lds[256];
    int i = blockIdx.x * 256 + threadIdx.x;
    int v = (i < n) ? data[i] : 0;
    lds[threadIdx.x] = v;
    __syncthreads();
#pragma unroll
    for (int off = 1; off < 256; off <<= 1) {
        int t = (threadIdx.x >= off) ? lds[threadIdx.x - off] : 0;
        __syncthreads();
        lds[threadIdx.x] += t;
        __syncthreads();
    }
    int incl = lds[threadIdx.x];
    if (i < n) data[i] = incl - v;
    if (threadIdx.x == 255) bsum[blockIdx.x] = incl;
}

__global__ __launch_bounds__(256) void scan2_kernel(int* __restrict__ bsum, int nb) {
    __shared__ int lds[256];
    int carry = 0;
    for (int base = 0; base < nb; base += 256) {
        int i = base + threadIdx.x;
        int v = (i < nb) ? bsum[i] : 0;
        lds[threadIdx.x] = v;
        __syncthreads();
#pragma unroll
        for (int off = 1; off < 256; off <<= 1) {
            int t = (threadIdx.x >= off) ? lds[threadIdx.x - off] : 0;
            __syncthreads();
            lds[threadIdx.x] += t;
            __syncthreads();
        }
        if (i < nb) bsum[i] = (lds[threadIdx.x] - v) + carry;
        int tot = lds[255];
        __syncthreads();
        carry += tot;
    }
}

__global__ __launch_bounds__(256) void scan3_kernel(int* __restrict__ row_ptr,
                                                    int* __restrict__ alloc,
                                                    const int* __restrict__ bsum, int n) {
    int i = blockIdx.x * 256 + threadIdx.x;
    if (i >= n) return;
    int v = row_ptr[i] + bsum[blockIdx.x];
    row_ptr[i] = v;
    alloc[i] = v;
}

__global__ __launch_bounds__(256) void scatter_kernel(const int* __restrict__ esrc,
                                                      const int* __restrict__ edst,
                                                      int* __restrict__ alloc,
                                                      int* __restrict__ csr_src) {
    int i = blockIdx.x * 256 + threadIdx.x;
    if (i >= E3) return;
    int r = i / NE;
    int d = edst[i];
    int pos = atomicAdd(&alloc[r * NN + d], 1);
    csr_src[pos] = esrc[i];
}

// ---------------- pack W into MFMA B-fragment order ----------------
// Bp[m][tile][lane][j]; tile = ct*4+kk; col = ct*16+(lane&15); k = kk*32+(lane>>4)*8+j
__global__ __launch_bounds__(256) void packW_kernel(const float* __restrict__ W1,
                                                    const float* __restrict__ W2,
                                                    unsigned short* __restrict__ Bp) {
    int idx = blockIdx.x * 256 + threadIdx.x;
    if (idx >= 6 * 32 * 64 * 8) return;
    int j = idx & 7;
    int l = (idx >> 3) & 63;
    int tile = (idx >> 9) & 31;
    int m = idx >> 14;
    int ct = tile >> 2, kk = tile & 3;
    int col = ct * 16 + (l & 15);
    int k = kk * 32 + (l >> 4) * 8 + j;
    const float* W = (m < 3) ? (W1 + (size_t)m * (F * F)) : (W2 + (size_t)(m - 3) * (F * F));
    Bp[idx] = f2bf(W[k * F + col]);
}

// ---------------- MFMA GEMM: Y[n,j](bf16) = A[n,:](fp32) @ W; B pre-packed ----------------
__global__ __launch_bounds__(256) void gemm_mfma_kernel(const float* __restrict__ A,
                                                        const unsigned short* __restrict__ Bp,
                                                        unsigned short* __restrict__ Y) {
    const int t = threadIdx.x;
    const int wv = t >> 6, lane = t & 63;
    const int lr = lane & 15;            // A row-in-tile / B,C col-in-tile
    const int lk = (lane >> 4) * 8;      // k offset within 32
    const int rowbase = blockIdx.x * 128 + wv * 32;
    const bf16x8* bp = (const bf16x8*)Bp;

    f32x4 acc[2][8];
#pragma unroll
    for (int rt = 0; rt < 2; ++rt)
#pragma unroll
        for (int ct = 0; ct < 8; ++ct) acc[rt][ct] = (f32x4){0.f, 0.f, 0.f, 0.f};

#pragma unroll
    for (int kk = 0; kk < 4; ++kk) {
        bf16x8 afr[2];
#pragma unroll
        for (int rt = 0; rt < 2; ++rt) {
            int r = rowbase + rt * 16 + lr;
            int rc = r < NN ? r : NN - 1;  // clamp; OOB rows discarded at store
            const float* ap = A + (size_t)rc * F + kk * 32 + lk;
            float4 f0 = *(const float4*)ap;
            float4 f1 = *(const float4*)(ap + 4);
            bf16x8 v;
            v[0] = (__bf16)f0.x; v[1] = (__bf16)f0.y; v[2] = (__bf16)f0.z; v[3] = (__bf16)f0.w;
            v[4] = (__bf16)f1.x; v[5] = (__bf16)f1.y; v[6] = (__bf16)f1.z; v[7] = (__bf16)f1.w;
            afr[rt] = v;
        }
#pragma unroll
        for (int ct = 0; ct < 8; ++ct) {
            bf16x8 b = bp[(ct * 4 + kk) * 64 + lane];
            acc[0][ct] = __builtin_amdgcn_mfma_f32_16x16x32_bf16(afr[0], b, acc[0][ct], 0, 0, 0);
            acc[1][ct] = __builtin_amdgcn_mfma_f32_16x16x32_bf16(afr[1], b, acc[1][ct], 0, 0, 0);
        }
    }

    const int crow = (lane >> 4) * 4;  // C/D: col = lane&15, row = (lane>>4)*4 + i
#pragma unroll
    for (int rt = 0; rt < 2; ++rt)
#pragma unroll
        for (int i = 0; i < 4; ++i) {
            int r = rowbase + rt * 16 + crow + i;
            if (r < NN) {
#pragma unroll
                for (int ct = 0; ct < 8; ++ct)
                    Y[(size_t)r * F + ct * 16 + lr] = f2bf(acc[rt][ct][i]);
            }
        }
}

// ---------------- el/er from bf16 feat
template <int H, int D>
__global__ __launch_bounds__(256) void el_er_kernel(const unsigned short* __restrict__ featb,
                                                    const float* __restrict__ al,
                                                    const float* __restrict__ ar,
                                                    float* __restrict__ el,
                                                    float* __restrict__ er) {
    int idx = blockIdx.x * 256 + threadIdx.x;  // idx = n*H + h
    if (idx >= NN * H) return;
    int h = idx & (H - 1);
    const uint4* fp = (const uint4*)(featb + (size_t)idx * D);
    const float4* ap = (const float4*)(al + h * D);
    const float4* bp = (const float4*)(ar + h * D);
    float sl = 0.f, sr = 0.f;
#pragma unroll
    for (int q = 0; q < D / 8; ++q) {
        uint4 u = fp[q];
        float f[8] = {bf2f((unsigned short)(u.x & 0xffff)), bf2f((unsigned short)(u.x >> 16)),
                      bf2f((unsigned short)(u.y & 0xffff)), bf2f((unsigned short)(u.y >> 16)),
                      bf2f((unsigned short)(u.z & 0xffff)), bf2f((unsigned short)(u.z >> 16)),
                      bf2f((unsigned short)(u.w & 0xffff)), bf2f((unsigned short)(u.w >> 16))};
        float4 a0 = ap[2 * q], a1 = ap[2 * q + 1];
        float4 b0 = bp[2 * q], b1 = bp[2 * q + 1];
        sl += f[0] * a0.x + f[1] * a0.y + f[2] * a0.z + f[3] * a0.w +
              f[4] * a1.x + f[5] * a1.y + f[6] * a1.z + f[7] * a1.w;
        sr += f[0] * b0.x + f[1] * b0.y + f[2] * b0.z + f[3] * b0.w +
              f[4] * b1.x + f[5] * b1.y + f[6] * b1.z + f[7] * b1.w;
    }
    el[idx] = sl;
    er[idx] = sr;
}

// ---------------- per-(dst,head) online softmax stats
template <int H>
__global__ __launch_bounds__(256) void stats_kernel(const int* __restrict__ row_ptr,
                                                    const int* __restrict__ csr_src,
                                                    const float* __restrict__ el,
                                                    const float* __restrict__ er,
                                                    float* __restrict__ mbuf,
                                                    float* __restrict__ dbuf, int rbase) {
    int t = blockIdx.x * 256 + threadIdx.x;  // t = d*H + h
    if (t >= NN * H) return;
    int d = t / H, h = t - (t / H) * H;
    int idx = rbase + d;
    int rs = row_ptr[idx];
    int re = (idx + 1 < M3) ? row_ptr[idx + 1] : E3;
    float erv = er[t];
    float m = -INFINITY, sum = 0.f;
    for (int i = rs; i < re; ++i) {
        int s = csr_src[i];
        float v = lrelu(el[s * H + h] + erv);
        float mn = fmaxf(m, v);
        sum = sum * __expf(m - mn) + __expf(v - mn);
        m = mn;
    }
    mbuf[t] = m;
    dbuf[t] = sum;
}

// ---------------- aggregation: one 64-lane wave per dst, lane covers f, f+64
template <int H, int ACCUM>
__global__ __launch_bounds__(256) void aggr_kernel(const int* __restrict__ row_ptr,
                                                   const int* __restrict__ csr_src,
                                                   const float* __restrict__ el,
                                                   const float* __restrict__ er,
                                                   const float* __restrict__ mbuf,
                                                   const float* __restrict__ dbuf,
                                                   const unsigned short* __restrict__ featb,
                                                   float* __restrict__ acc, int rbase) {
    const int gid = blockIdx.x * 256 + threadIdx.x;
    const int d = gid >> 6;
    const int lane = gid & 63;
    if (d >= NN) return;
    const int idx = rbase + d;
    const int rs = row_ptr[idx];
    const int re = (idx + 1 < M3) ? row_ptr[idx + 1] : E3;
    const int f0 = lane, f1 = lane + 64;
    const int D = F / H;
    const int h0 = f0 / D, h1 = f1 / D;
    const float er0 = er[d * H + h0], er1 = er[d * H + h1];
    const float m0 = mbuf[d * H + h0], m1 = mbuf[d * H + h1];
    const float rd0 = 1.f / fmaxf(dbuf[d * H + h0], 1e-9f);
    const float rd1 = 1.f / fmaxf(dbuf[d * H + h1], 1e-9f);
    float a0 = 0.f, a1 = 0.f;
    for (int i = rs; i < re; ++i) {
        int s = csr_src[i];
        const unsigned short* fr = featb + (size_t)s * F;
        float v0 = lrelu(el[s * H + h0] + er0);
        float v1 = lrelu(el[s * H + h1] + er1);
        a0 += __expf(v0 - m0) * rd0 * bf2f(fr[f0]);
        a1 += __expf(v1 - m1) * rd1 * bf2f(fr[f1]);
    }
    size_t o = (size_t)d * F;
    if (ACCUM) {
        acc[o + f0] += a0;
        acc[o + f1] += a1;
    } else {
        acc[o + f0] = a0;
        acc[o + f1] = a1;
    }
}

// h1 = elu(acc/3 + x + mean_bias), in place
__global__ __launch_bounds__(256) void finalize1_kernel(float* __restrict__ acc,
                                                        const float* __restrict__ x,
                                                        const float* __restrict__ b1) {
    size_t i = (size_t)blockIdx.x * 256 + threadIdx.x;
    if (i >= (size_t)NN * F) return;
    int f = (int)(i & 127);
    float bsum = (b1[f] + b1[F + f] + b1[2 * F + f]) * (1.f / 3.f);
    float v = acc[i] * (1.f / 3.f) + x[i] + bsum;
    acc[i] = v > 0.f ? v : (__expf(v) - 1.f);
}

// out = out/3 + h1 + mean_bias
__global__ __launch_bounds__(256) void finalize2_kernel(float* __restrict__ out,
                                                        const float* __restrict__ h1,
                                                        const float* __restrict__ b2) {
    size_t i = (size_t)blockIdx.x * 256 + threadIdx.x;
    if (i >= (size_t)NN * F) return;
    int f = (int)(i & 127);
    float bsum = (b2[f] + b2[F + f] + b2[2 * F + f]) * (1.f / 3.f);
    out[i] = out[i] * (1.f / 3.f) + h1[i] + bsum;
}

extern "C" void kernel_launch(void* const* d_in, const int* in_sizes, int n_in,
                              void* d_out, int out_size, void* d_ws, size_t ws_size,
                              hipStream_t stream) {
    const float* x   = (const float*)d_in[0];
    const int* esrc  = (const int*)d_in[1];
    const int* edst  = (const int*)d_in[2];
    const float* W1  = (const float*)d_in[3];
    const float* b1  = (const float*)d_in[4];
    const float* al1 = (const float*)d_in[5];
    const float* ar1 = (const float*)d_in[6];
    const float* W2  = (const float*)d_in[7];
    const float* b2  = (const float*)d_in[8];
    const float* al2 = (const float*)d_in[9];
    const float* ar2 = (const float*)d_in[10];
    float* out = (float*)d_out;

    // workspace layout
    char* p = (char*)d_ws;
    unsigned short* featb = (unsigned short*)p;         p += (size_t)NN * F * 2;       // 25.6 MB
    float* acc   = (float*)p;                           p += (size_t)NN * F * 4;       // 51.2 MB
    float* el    = (float*)p;                           p += (size_t)NN * 4 * 4;
    float* er    = (float*)p;                           p += (size_t)NN * 4 * 4;
    float* mbuf  = (float*)p;                           p += (size_t)NN * 4 * 4;
    float* dbuf  = (float*)p;                           p += (size_t)NN * 4 * 4;
    int* row_ptr = (int*)p;                             p += (size_t)M3 * 4;
    int* alloc   = (int*)p;                             p += (size_t)M3 * 4;
    int* bsum    = (int*)p;                             p += (size_t)((NB1 + 63) & ~63) * 4;
    int* csr_src = (int*)p;                             p += (size_t)E3 * 4;
    unsigned short* Bpack = (unsigned short*)p;         p += (size_t)6 * F * F * 2;    // 196 KB

    dim3 b256(256);
    const int eg3 = (E3 + 255) / 256;
    const int gemm_grid = (NN + 127) / 128;
    const int ng4 = (NN * 4 + 255) / 256;
    const int ng1 = (NN + 255) / 256;
    const int agg = (NN * 64 + 255) / 256;
    const int fg = (int)(((size_t)NN * F + 255) / 256);

    // ---- build CSR by dst (shared by both layers) + pack weights
    hipMemsetAsync(row_ptr, 0, (size_t)M3 * 4, stream);
    packW_kernel<<<(6 * F * F + 255) / 256, b256, 0, stream>>>(W1, W2, Bpack);
    hist_kernel<<<eg3, b256, 0, stream>>>(edst, row_ptr);
    scan1_kernel<<<NB1, b256, 0, stream>>>(row_ptr, bsum, M3);
    scan2_kernel<<<1, b256, 0, stream>>>(bsum, NB1);
    scan3_kernel<<<NB1, b256, 0, stream>>>(row_ptr, alloc, bsum, M3);
    scatter_kernel<<<eg3, b256, 0, stream>>>(esrc, edst, alloc, csr_src);

    // ---- layer 1: GATConv(128 -> 32, 4 heads) per relation, mean
    for (int r = 0; r < NR; ++r) {
        int rbase = r * NN;
        gemm_mfma_kernel<<<gemm_grid, b256, 0, stream>>>(x, Bpack + (size_t)r * F * F, featb);
        el_er_kernel<4, 32><<<ng4, b256, 0, stream>>>(featb, al1 + r * F, ar1 + r * F, el, er);
        stats_kernel<4><<<ng4, b256, 0, stream>>>(row_ptr, csr_src, el, er, mbuf, dbuf, rbase);
        if (r == 0)
            aggr_kernel<4, 0><<<agg, b256, 0, stream>>>(row_ptr, csr_src, el, er, mbuf, dbuf, featb, acc, rbase);
        else
            aggr_kernel<4, 1><<<agg, b256, 0, stream>>>(row_ptr, csr_src, el, er, mbuf, dbuf, featb, acc, rbase);
    }
    finalize1_kernel<<<fg, b256, 0, stream>>>(acc, x, b1);  // acc := h1 (fp32)

    // ---- layer 2: GATConv(128 -> 128, 1 head) per relation, mean
    for (int r = 0; r < NR; ++r) {
        int rbase = r * NN;
        gemm_mfma_kernel<<<gemm_grid, b256, 0, stream>>>(acc, Bpack + (size_t)(3 + r) * F * F, featb);
        el_er_kernel<1, 128><<<ng1, b256, 0, stream>>>(featb, al2 + r * F, ar2 + r * F, el, er);
        stats_kernel<1><<<ng1, b256, 0, stream>>>(row_ptr, csr_src, el, er, mbuf, dbuf, rbase);
        if (r == 0)
            aggr_kernel<1, 0><<<agg, b256, 0, stream>>>(row_ptr, csr_src, el, er, mbuf, dbuf, featb, out, rbase);
        else
            aggr_kernel<1, 1><<<agg, b256, 0, stream>>>(row_ptr, csr_src, el, er, mbuf, dbuf, featb, out, rbase);
    }
    finalize2_kernel<<<fg, b256, 0, stream>>>(out, acc, b2);
}

// Round 8
// 1047.851 us; speedup vs baseline: 4.0882x; 1.1650x over previous
//
#include <hip/hip_runtime.h>
#include <hip/hip_bf16.h>

#define NN 100000
#define NE 800000
#define NR 3
#define F 128
#define M3 (NR * NN)               // 300000 CSR rows across relations
#define E3 (NR * NE)               // 2400000 edges total
#define NB1 ((M3 + 255) / 256)     // scan blocks

typedef __bf16 bf16x8 __attribute__((ext_vector_type(8)));
typedef float f32x4 __attribute__((ext_vector_type(4)));

__device__ __forceinline__ float lrelu(float v) { return v >= 0.f ? v : 0.2f * v; }
__device__ __forceinline__ float bf2f(unsigned short u) {
    return __uint_as_float(((unsigned)u) << 16);
}
__device__ __forceinline__ unsigned short f2bf(float f) {
    __hip_bfloat16 h = __float2bfloat16(f);
    unsigned short u;
    __builtin_memcpy(&u, &h, 2);
    return u;
}

// ---------------- CSR build ----------------
__global__ __launch_bounds__(256) void hist_kernel(const int* __restrict__ edst,
                                                   int* __restrict__ counts) {
    int i = blockIdx.x * 256 + threadIdx.x;
    if (i >= E3) return;
    int r = i / NE;
    atomicAdd(&counts[r * NN + edst[i]], 1);
}

__global__ __launch_bounds__(256) void scan1_kernel(int* __restrict__ data,
                                                    int* __restrict__ bsum, int n) {
    __shared__ int lds[256];
    int i = blockIdx.x * 256 + threadIdx.x;
    int v = (i < n) ? data[i] : 0;
    lds[threadIdx.x] = v;
    __syncthreads();
#pragma unroll
    for (int off = 1; off < 256; off <<= 1) {
        int t = (threadIdx.x >= off) ? lds[threadIdx.x - off] : 0;
        __syncthreads();
        lds[threadIdx.x] += t;
        __syncthreads();
    }
    int incl = lds[threadIdx.x];
    if (i < n) data[i] = incl - v;
    if (threadIdx.x == 255) bsum[blockIdx.x] = incl;
}

__global__ __launch_bounds__(256) void scan2_kernel(int* __restrict__ bsum, int nb) {
    __shared__ int lds[256];
    int carry = 0;
    for (int base = 0; base < nb; base += 256) {
        int i = base + threadIdx.x;
        int v = (i < nb) ? bsum[i] : 0;
        lds[threadIdx.x] = v;
        __syncthreads();
#pragma unroll
        for (int off = 1; off < 256; off <<= 1) {
            int t = (threadIdx.x >= off) ? lds[threadIdx.x - off] : 0;
            __syncthreads();
            lds[threadIdx.x] += t;
            __syncthreads();
        }
        if (i < nb) bsum[i] = (lds[threadIdx.x] - v) + carry;
        int tot = lds[255];
        __syncthreads();
        carry += tot;
    }
}

__global__ __launch_bounds__(256) void scan3_kernel(int* __restrict__ row_ptr,
                                                    int* __restrict__ alloc,
                                                    const int* __restrict__ bsum, int n) {
    int i = blockIdx.x * 256 + threadIdx.x;
    if (i >= n) return;
    int v = row_ptr[i] + bsum[blockIdx.x];
    row_ptr[i] = v;
    alloc[i] = v;
}

__global__ __launch_bounds__(256) void scatter_kernel(const int* __restrict__ esrc,
                                                      const int* __restrict__ edst,
                                                      int* __restrict__ alloc,
                                                      int* __restrict__ csr_src) {
    int i = blockIdx.x * 256 + threadIdx.x;
    if (i >= E3) return;
    int r = i / NE;
    int d = edst[i];
    int pos = atomicAdd(&alloc[r * NN + d], 1);
    csr_src[pos] = esrc[i];
}

// ---------------- pack W into MFMA B-fragment order ----------------
// Bp[m][tile][lane][j]; tile = ct*4+kk; col = ct*16+(lane&15); k = kk*32+(lane>>4)*8+j
__global__ __launch_bounds__(256) void packW_kernel(const float* __restrict__ W1,
                                                    const float* __restrict__ W2,
                                                    unsigned short* __restrict__ Bp) {
    int idx = blockIdx.x * 256 + threadIdx.x;
    if (idx >= 6 * 32 * 64 * 8) return;
    int j = idx & 7;
    int l = (idx >> 3) & 63;
    int tile = (idx >> 9) & 31;
    int m = idx >> 14;
    int ct = tile >> 2, kk = tile & 3;
    int col = ct * 16 + (l & 15);
    int k = kk * 32 + (l >> 4) * 8 + j;
    const float* W = (m < 3) ? (W1 + (size_t)m * (F * F)) : (W2 + (size_t)(m - 3) * (F * F));
    Bp[idx] = f2bf(W[k * F + col]);
}

// ---------------- fused MFMA GEMM: stage A once (LDS, swizzled bf16), 3 relations
__global__ __launch_bounds__(256) void gemm_fused_kernel(const float* __restrict__ A,
                                                         const unsigned short* __restrict__ Bp,
                                                         unsigned short* __restrict__ Y) {
    __shared__ __align__(16) unsigned short alds[128 * 128];  // 32 KB, XOR-swizzled
    const int t = threadIdx.x;
    const int row0 = blockIdx.x * 128;
    // stage A fp32 -> bf16 LDS, coalesced float4 loads, swizzle byte ^= (row&7)<<4
#pragma unroll
    for (int it = 0; it < 16; ++it) {
        int g = it * 256 + t;           // float4 granule id, 4096 total
        int row = g >> 5, k4 = g & 31;  // k = k4*4
        int gr = row0 + row;
        float4 v;
        if (gr < NN) v = *(const float4*)(A + (size_t)gr * F + k4 * 4);
        else v = make_float4(0.f, 0.f, 0.f, 0.f);
        unsigned int lo = (unsigned)f2bf(v.x) | ((unsigned)f2bf(v.y) << 16);
        unsigned int hi = (unsigned)f2bf(v.z) | ((unsigned)f2bf(v.w) << 16);
        int k2 = k4 * 8;  // byte offset within 256-B row
        int byte = row * 256 + ((k2 & ~15) ^ ((row & 7) << 4)) + (k2 & 15);
        *(uint2*)((char*)alds + byte) = make_uint2(lo, hi);
    }
    __syncthreads();

    const int wv = t >> 6, lane = t & 63;
    const int lr = lane & 15;        // A row-in-tile / C col-in-tile
    const int lkq = lane >> 4;       // k quarter
    for (int m = 0; m < NR; ++m) {
        const bf16x8* bp = (const bf16x8*)(Bp + (size_t)m * F * F);
        f32x4 acc[2][8];
#pragma unroll
        for (int rt = 0; rt < 2; ++rt)
#pragma unroll
            for (int ct = 0; ct < 8; ++ct) acc[rt][ct] = (f32x4){0.f, 0.f, 0.f, 0.f};
#pragma unroll
        for (int kk = 0; kk < 4; ++kk) {
            bf16x8 afr[2];
#pragma unroll
            for (int rt = 0; rt < 2; ++rt) {
                int row = wv * 32 + rt * 16 + lr;
                int k2 = kk * 64 + lkq * 16;  // 16-B aligned
                int byte = row * 256 + (k2 ^ ((row & 7) << 4));
                afr[rt] = *(const bf16x8*)((const char*)alds + byte);
            }
#pragma unroll
            for (int ct = 0; ct < 8; ++ct) {
                bf16x8 b = bp[(ct * 4 + kk) * 64 + lane];
                acc[0][ct] = __builtin_amdgcn_mfma_f32_16x16x32_bf16(afr[0], b, acc[0][ct], 0, 0, 0);
                acc[1][ct] = __builtin_amdgcn_mfma_f32_16x16x32_bf16(afr[1], b, acc[1][ct], 0, 0, 0);
            }
        }
        unsigned short* Yp = Y + (size_t)m * NN * F;
        const int crow = lkq * 4;  // C/D: col = lane&15, row = (lane>>4)*4 + i
#pragma unroll
        for (int rt = 0; rt < 2; ++rt)
#pragma unroll
            for (int i = 0; i < 4; ++i) {
                int rr = row0 + wv * 32 + rt * 16 + crow + i;
                if (rr < NN) {
#pragma unroll
                    for (int ct = 0; ct < 8; ++ct)
                        Yp[(size_t)rr * F + ct * 16 + lr] = f2bf(acc[rt][ct][i]);
                }
            }
    }
}

// ---------------- el/er, all 3 relations; el[r*NN*H + n*H + h]
template <int H, int D>
__global__ __launch_bounds__(256) void el_er_fused_kernel(const unsigned short* __restrict__ featb,
                                                          const float* __restrict__ al,
                                                          const float* __restrict__ ar,
                                                          float* __restrict__ el,
                                                          float* __restrict__ er) {
    int idx = blockIdx.x * 256 + threadIdx.x;  // over NR*NN*H
    if (idx >= NR * NN * H) return;
    int r = idx / (NN * H);
    int w = idx - r * (NN * H);
    int h = w & (H - 1);
    const uint4* fp = (const uint4*)(featb + (size_t)r * NN * F + (size_t)w * D);
    const float4* ap = (const float4*)(al + r * F + h * D);
    const float4* bp = (const float4*)(ar + r * F + h * D);
    float sl = 0.f, sr = 0.f;
#pragma unroll
    for (int q = 0; q < D / 8; ++q) {
        uint4 u = fp[q];
        float f[8] = {bf2f((unsigned short)(u.x & 0xffff)), bf2f((unsigned short)(u.x >> 16)),
                      bf2f((unsigned short)(u.y & 0xffff)), bf2f((unsigned short)(u.y >> 16)),
                      bf2f((unsigned short)(u.z & 0xffff)), bf2f((unsigned short)(u.z >> 16)),
                      bf2f((unsigned short)(u.w & 0xffff)), bf2f((unsigned short)(u.w >> 16))};
        float4 a0 = ap[2 * q], a1 = ap[2 * q + 1];
        float4 b0 = bp[2 * q], b1 = bp[2 * q + 1];
        sl += f[0] * a0.x + f[1] * a0.y + f[2] * a0.z + f[3] * a0.w +
              f[4] * a1.x + f[5] * a1.y + f[6] * a1.z + f[7] * a1.w;
        sr += f[0] * b0.x + f[1] * b0.y + f[2] * b0.z + f[3] * b0.w +
              f[4] * b1.x + f[5] * b1.y + f[6] * b1.z + f[7] * b1.w;
    }
    el[idx] = sl;
    er[idx] = sr;
}

// ---------------- online softmax stats, all 3 relations
template <int H>
__global__ __launch_bounds__(256) void stats_fused_kernel(const int* __restrict__ row_ptr,
                                                          const int* __restrict__ csr_src,
                                                          const float* __restrict__ el,
                                                          const float* __restrict__ er,
                                                          float* __restrict__ mbuf,
                                                          float* __restrict__ dbuf) {
    int t = blockIdx.x * 256 + threadIdx.x;  // t = r*NN*H + d*H + h
    if (t >= NR * NN * H) return;
    int r = t / (NN * H);
    int w = t - r * (NN * H);
    int d = w / H, h = w - (w / H) * H;
    int idx = r * NN + d;
    int rs = row_ptr[idx];
    int re = (idx + 1 < M3) ? row_ptr[idx + 1] : E3;
    const float* elr = el + (size_t)r * NN * H;
    float erv = er[t];
    float m = -INFINITY, sum = 0.f;
    for (int i = rs; i < re; ++i) {
        int s = csr_src[i];
        float v = lrelu(elr[s * H + h] + erv);
        float mn = fmaxf(m, v);
        sum = sum * __expf(m - mn) + __expf(v - mn);
        m = mn;
    }
    mbuf[t] = m;
    dbuf[t] = sum;
}

// ---------------- fused aggregation: wave per dst, loops relations, writes once
// FIN==1: out = elu(sum/3 + resid + meanbias)   FIN==2: out = sum/3 + resid + meanbias
// resid may alias outp: each element is read & written by the same thread only.
template <int H, int FIN>
__global__ __launch_bounds__(256) void aggr_fused_kernel(const int* __restrict__ row_ptr,
                                                         const int* __restrict__ csr_src,
                                                         const float* __restrict__ el,
                                                         const float* __restrict__ er,
                                                         const float* __restrict__ mbuf,
                                                         const float* __restrict__ dbuf,
                                                         const unsigned short* __restrict__ featb,
                                                         const float* __restrict__ resid,
                                                         const float* __restrict__ bias,
                                                         float* __restrict__ outp) {
    const int gid = blockIdx.x * 256 + threadIdx.x;
    const int d = gid >> 6;
    const int lane = gid & 63;
    if (d >= NN) return;
    const int D = F / H;
    const int f0 = lane, f1 = lane + 64;
    const int h0 = f0 / D, h1 = f1 / D;
    float a0 = 0.f, a1 = 0.f;
    for (int r = 0; r < NR; ++r) {
        const int idx = r * NN + d;
        const int rs = row_ptr[idx];
        const int re = (idx + 1 < M3) ? row_ptr[idx + 1] : E3;
        const int tb = r * NN * H + d * H;
        const float er0 = er[tb + h0], er1 = er[tb + h1];
        const float m0 = mbuf[tb + h0], m1 = mbuf[tb + h1];
        const float rd0 = 1.f / fmaxf(dbuf[tb + h0], 1e-9f);
        const float rd1 = 1.f / fmaxf(dbuf[tb + h1], 1e-9f);
        const float* elr = el + (size_t)r * NN * H;
        const unsigned short* fb = featb + (size_t)r * NN * F;
        for (int i = rs; i < re; ++i) {
            int s = csr_src[i];
            const unsigned short* fr = fb + (size_t)s * F;
            float v0 = lrelu(elr[s * H + h0] + er0);
            float v1 = lrelu(elr[s * H + h1] + er1);
            a0 += __expf(v0 - m0) * rd0 * bf2f(fr[f0]);
            a1 += __expf(v1 - m1) * rd1 * bf2f(fr[f1]);
        }
    }
    const float third = 1.f / 3.f;
    size_t o = (size_t)d * F;
    float bs0 = (bias[f0] + bias[F + f0] + bias[2 * F + f0]) * third;
    float bs1 = (bias[f1] + bias[F + f1] + bias[2 * F + f1]) * third;
    float v0 = a0 * third + resid[o + f0] + bs0;
    float v1 = a1 * third + resid[o + f1] + bs1;
    if (FIN == 1) {
        outp[o + f0] = v0 > 0.f ? v0 : (__expf(v0) - 1.f);
        outp[o + f1] = v1 > 0.f ? v1 : (__expf(v1) - 1.f);
    } else {
        outp[o + f0] = v0;
        outp[o + f1] = v1;
    }
}

extern "C" void kernel_launch(void* const* d_in, const int* in_sizes, int n_in,
                              void* d_out, int out_size, void* d_ws, size_t ws_size,
                              hipStream_t stream) {
    const float* x   = (const float*)d_in[0];
    const int* esrc  = (const int*)d_in[1];
    const int* edst  = (const int*)d_in[2];
    const float* W1  = (const float*)d_in[3];
    const float* b1  = (const float*)d_in[4];
    const float* al1 = (const float*)d_in[5];
    const float* ar1 = (const float*)d_in[6];
    const float* W2  = (const float*)d_in[7];
    const float* b2  = (const float*)d_in[8];
    const float* al2 = (const float*)d_in[9];
    const float* ar2 = (const float*)d_in[10];
    float* out = (float*)d_out;

    // workspace layout (~108.2 MB; proven-safe ws_size >= 108.8 MB from round 1)
    // h1 lives in d_out: layer-1 aggr writes it; layer-2 gemm reads it as A;
    // layer-2 aggr reads it as resid and overwrites d_out in the same thread.
    char* p = (char*)d_ws;
    unsigned short* featb = (unsigned short*)p;  p += (size_t)NR * NN * F * 2;  // 76.8 MB
    float* el    = (float*)p;                    p += (size_t)NR * NN * 4 * 4;  // 4.8 MB
    float* er    = (float*)p;                    p += (size_t)NR * NN * 4 * 4;
    float* mbuf  = (float*)p;                    p += (size_t)NR * NN * 4 * 4;
    float* dbuf  = (float*)p;                    p += (size_t)NR * NN * 4 * 4;
    int* row_ptr = (int*)p;                      p += (size_t)M3 * 4;           // 1.2 MB
    int* alloc   = (int*)p;                      p += (size_t)M3 * 4;           // 1.2 MB
    int* bsum    = (int*)p;                      p += (size_t)((NB1 + 63) & ~63) * 4;
    int* csr_src = (int*)p;                      p += (size_t)E3 * 4;           // 9.6 MB
    unsigned short* Bpack = (unsigned short*)p;  p += (size_t)6 * F * F * 2;    // 0.2 MB
    float* h1 = out;

    dim3 b256(256);
    const int eg3 = (E3 + 255) / 256;
    const int gemm_grid = (NN + 127) / 128;
    const int g3h4 = (NR * NN * 4 + 255) / 256;
    const int g3h1 = (NR * NN * 1 + 255) / 256;
    const int agg = (NN * 64 + 255) / 256;

    // ---- build CSR by dst (shared by both layers) + pack weights
    hipMemsetAsync(row_ptr, 0, (size_t)M3 * 4, stream);
    packW_kernel<<<(6 * F * F + 255) / 256, b256, 0, stream>>>(W1, W2, Bpack);
    hist_kernel<<<eg3, b256, 0, stream>>>(edst, row_ptr);
    scan1_kernel<<<NB1, b256, 0, stream>>>(row_ptr, bsum, M3);
    scan2_kernel<<<1, b256, 0, stream>>>(bsum, NB1);
    scan3_kernel<<<NB1, b256, 0, stream>>>(row_ptr, alloc, bsum, M3);
    scatter_kernel<<<eg3, b256, 0, stream>>>(esrc, edst, alloc, csr_src);

    // ---- layer 1: GATConv(128 -> 32, 4 heads) x3 relations, mean, +res +bias, ELU
    gemm_fused_kernel<<<gemm_grid, b256, 0, stream>>>(x, Bpack, featb);
    el_er_fused_kernel<4, 32><<<g3h4, b256, 0, stream>>>(featb, al1, ar1, el, er);
    stats_fused_kernel<4><<<g3h4, b256, 0, stream>>>(row_ptr, csr_src, el, er, mbuf, dbuf);
    aggr_fused_kernel<4, 1><<<agg, b256, 0, stream>>>(row_ptr, csr_src, el, er, mbuf, dbuf,
                                                      featb, x, b1, h1);

    // ---- layer 2: GATConv(128 -> 128, 1 head) x3 relations, mean, +res +bias
    gemm_fused_kernel<<<gemm_grid, b256, 0, stream>>>(h1, Bpack + (size_t)3 * F * F, featb);
    el_er_fused_kernel<1, 128><<<g3h1, b256, 0, stream>>>(featb, al2, ar2, el, er);
    stats_fused_kernel<1><<<g3h1, b256, 0, stream>>>(row_ptr, csr_src, el, er, mbuf, dbuf);
    aggr_fused_kernel<1, 2><<<agg, b256, 0, stream>>>(row_ptr, csr_src, el, er, mbuf, dbuf,
                                                      featb, h1, b2, out);
}

// Round 10
// 787.607 us; speedup vs baseline: 5.4390x; 1.3304x over previous
//
#include <hip/hip_runtime.h>
#include <hip/hip_bf16.h>

#define NN 100000
#define NE 800000
#define NR 3
#define F 128
#define M3 (NR * NN)               // 300000 CSR rows across relations
#define E3 (NR * NE)               // 2400000 edges total
#define NB1 ((M3 + 255) / 256)     // scan blocks
#define NPASS 8
#define PW ((NN + NPASS - 1) / NPASS)   // dst window per scatter pass

typedef __bf16 bf16x8 __attribute__((ext_vector_type(8)));
typedef float f32x4 __attribute__((ext_vector_type(4)));

__device__ __forceinline__ float lrelu(float v) { return v >= 0.f ? v : 0.2f * v; }
__device__ __forceinline__ float bf2f(unsigned short u) {
    return __uint_as_float(((unsigned)u) << 16);
}
__device__ __forceinline__ unsigned short f2bf(float f) {
    __hip_bfloat16 h = __float2bfloat16(f);
    unsigned short u;
    __builtin_memcpy(&u, &h, 2);
    return u;
}

// ---------------- CSR build ----------------
__global__ __launch_bounds__(256) void hist_kernel(const int* __restrict__ edst,
                                                   int* __restrict__ counts) {
    int i = blockIdx.x * 256 + threadIdx.x;
    if (i >= E3) return;
    int r = i / NE;
    atomicAdd(&counts[r * NN + edst[i]], 1);
}

__global__ __launch_bounds__(256) void scan1_kernel(int* __restrict__ data,
                                                    int* __restrict__ bsum, int n) {
    __shared__ int lds[256];
    int i = blockIdx.x * 256 + threadIdx.x;
    int v = (i < n) ? data[i] : 0;
    lds[threadIdx.x] = v;
    __syncthreads();
#pragma unroll
    for (int off = 1; off < 256; off <<= 1) {
        int t = (threadIdx.x >= off) ? lds[threadIdx.x - off] : 0;
        __syncthreads();
        lds[threadIdx.x] += t;
        __syncthreads();
    }
    int incl = lds[threadIdx.x];
    if (i < n) data[i] = incl - v;
    if (threadIdx.x == 255) bsum[blockIdx.x] = incl;
}

__global__ __launch_bounds__(256) void scan2_kernel(int* __restrict__ bsum, int nb) {
    __shared__ int lds[256];
    int carry = 0;
    for (int base = 0; base < nb; base += 256) {
        int i = base + threadIdx.x;
        int v = (i < nb) ? bsum[i] : 0;
        lds[threadIdx.x] = v;
        __syncthreads();
#pragma unroll
        for (int off = 1; off < 256; off <<= 1) {
            int t = (threadIdx.x >= off) ? lds[threadIdx.x - off] : 0;
            __syncthreads();
            lds[threadIdx.x] += t;
            __syncthreads();
        }
        if (i < nb) bsum[i] = (lds[threadIdx.x] - v) + carry;
        int tot = lds[255];
        __syncthreads();
        carry += tot;
    }
}

__global__ __launch_bounds__(256) void scan3_kernel(int* __restrict__ row_ptr,
                                                    int* __restrict__ alloc,
                                                    const int* __restrict__ bsum, int n) {
    int i = blockIdx.x * 256 + threadIdx.x;
    if (i >= n) return;
    int v = row_ptr[i] + bsum[blockIdx.x];
    row_ptr[i] = v;
    alloc[i] = v;
}

// windowed scatter: only edges whose dst falls in [pass*PW, (pass+1)*PW) are
// written this pass -> active CSR write region ~1.2 MB, lines fully filled.
__global__ __launch_bounds__(256) void scatter_pass_kernel(const int* __restrict__ esrc,
                                                           const int* __restrict__ edst,
                                                           int* __restrict__ alloc,
                                                           int* __restrict__ csr_src,
                                                           int lo) {
    int i = blockIdx.x * 256 + threadIdx.x;
    if (i >= E3) return;
    int d = edst[i];
    if (d < lo || d >= lo + PW) return;
    int r = i / NE;
    int pos = atomicAdd(&alloc[r * NN + d], 1);
    csr_src[pos] = esrc[i];
}

// ---------------- pack W into MFMA B-fragment order ----------------
__global__ __launch_bounds__(256) void packW_kernel(const float* __restrict__ W1,
                                                    const float* __restrict__ W2,
                                                    unsigned short* __restrict__ Bp) {
    int idx = blockIdx.x * 256 + threadIdx.x;
    if (idx >= 6 * 32 * 64 * 8) return;
    int j = idx & 7;
    int l = (idx >> 3) & 63;
    int tile = (idx >> 9) & 31;
    int m = idx >> 14;
    int ct = tile >> 2, kk = tile & 3;
    int col = ct * 16 + (l & 15);
    int k = kk * 32 + (l >> 4) * 8 + j;
    const float* W = (m < 3) ? (W1 + (size_t)m * (F * F)) : (W2 + (size_t)(m - 3) * (F * F));
    Bp[idx] = f2bf(W[k * F + col]);
}

// ---------------- fused MFMA GEMM: stage A once (LDS, swizzled bf16), 3 relations
__global__ __launch_bounds__(256) void gemm_fused_kernel(const float* __restrict__ A,
                                                         const unsigned short* __restrict__ Bp,
                                                         unsigned short* __restrict__ Y) {
    __shared__ __align__(16) unsigned short alds[128 * 128];  // 32 KB, XOR-swizzled
    const int t = threadIdx.x;
    const int row0 = blockIdx.x * 128;
#pragma unroll
    for (int it = 0; it < 16; ++it) {
        int g = it * 256 + t;
        int row = g >> 5, k4 = g & 31;
        int gr = row0 + row;
        float4 v;
        if (gr < NN) v = *(const float4*)(A + (size_t)gr * F + k4 * 4);
        else v = make_float4(0.f, 0.f, 0.f, 0.f);
        unsigned int lo = (unsigned)f2bf(v.x) | ((unsigned)f2bf(v.y) << 16);
        unsigned int hi = (unsigned)f2bf(v.z) | ((unsigned)f2bf(v.w) << 16);
        int k2 = k4 * 8;
        int byte = row * 256 + ((k2 & ~15) ^ ((row & 7) << 4)) + (k2 & 15);
        *(uint2*)((char*)alds + byte) = make_uint2(lo, hi);
    }
    __syncthreads();

    const int wv = t >> 6, lane = t & 63;
    const int lr = lane & 15;
    const int lkq = lane >> 4;
    for (int m = 0; m < NR; ++m) {
        const bf16x8* bp = (const bf16x8*)(Bp + (size_t)m * F * F);
        f32x4 acc[2][8];
#pragma unroll
        for (int rt = 0; rt < 2; ++rt)
#pragma unroll
            for (int ct = 0; ct < 8; ++ct) acc[rt][ct] = (f32x4){0.f, 0.f, 0.f, 0.f};
#pragma unroll
        for (int kk = 0; kk < 4; ++kk) {
            bf16x8 afr[2];
#pragma unroll
            for (int rt = 0; rt < 2; ++rt) {
                int row = wv * 32 + rt * 16 + lr;
                int k2 = kk * 64 + lkq * 16;
                int byte = row * 256 + (k2 ^ ((row & 7) << 4));
                afr[rt] = *(const bf16x8*)((const char*)alds + byte);
            }
#pragma unroll
            for (int ct = 0; ct < 8; ++ct) {
                bf16x8 b = bp[(ct * 4 + kk) * 64 + lane];
                acc[0][ct] = __builtin_amdgcn_mfma_f32_16x16x32_bf16(afr[0], b, acc[0][ct], 0, 0, 0);
                acc[1][ct] = __builtin_amdgcn_mfma_f32_16x16x32_bf16(afr[1], b, acc[1][ct], 0, 0, 0);
            }
        }
        unsigned short* Yp = Y + (size_t)m * NN * F;
        const int crow = lkq * 4;
#pragma unroll
        for (int rt = 0; rt < 2; ++rt)
#pragma unroll
            for (int i = 0; i < 4; ++i) {
                int rr = row0 + wv * 32 + rt * 16 + crow + i;
                if (rr < NN) {
#pragma unroll
                    for (int ct = 0; ct < 8; ++ct)
                        Yp[(size_t)rr * F + ct * 16 + lr] = f2bf(acc[rt][ct][i]);
                }
            }
    }
}

// ---------------- el/er, all 3 relations; el[r*NN*H + n*H + h]
template <int H, int D>
__global__ __launch_bounds__(256) void el_er_fused_kernel(const unsigned short* __restrict__ featb,
                                                          const float* __restrict__ al,
                                                          const float* __restrict__ ar,
                                                          float* __restrict__ el,
                                                          float* __restrict__ er) {
    int idx = blockIdx.x * 256 + threadIdx.x;
    if (idx >= NR * NN * H) return;
    int r = idx / (NN * H);
    int w = idx - r * (NN * H);
    int h = w & (H - 1);
    const uint4* fp = (const uint4*)(featb + (size_t)r * NN * F + (size_t)w * D);
    const float4* ap = (const float4*)(al + r * F + h * D);
    const float4* bp = (const float4*)(ar + r * F + h * D);
    float sl = 0.f, sr = 0.f;
#pragma unroll
    for (int q = 0; q < D / 8; ++q) {
        uint4 u = fp[q];
        float f[8] = {bf2f((unsigned short)(u.x & 0xffff)), bf2f((unsigned short)(u.x >> 16)),
                      bf2f((unsigned short)(u.y & 0xffff)), bf2f((unsigned short)(u.y >> 16)),
                      bf2f((unsigned short)(u.z & 0xffff)), bf2f((unsigned short)(u.z >> 16)),
                      bf2f((unsigned short)(u.w & 0xffff)), bf2f((unsigned short)(u.w >> 16))};
        float4 a0 = ap[2 * q], a1 = ap[2 * q + 1];
        float4 b0 = bp[2 * q], b1 = bp[2 * q + 1];
        sl += f[0] * a0.x + f[1] * a0.y + f[2] * a0.z + f[3] * a0.w +
              f[4] * a1.x + f[5] * a1.y + f[6] * a1.z + f[7] * a1.w;
        sr += f[0] * b0.x + f[1] * b0.y + f[2] * b0.z + f[3] * b0.w +
              f[4] * b1.x + f[5] * b1.y + f[6] * b1.z + f[7] * b1.w;
    }
    el[idx] = sl;
    er[idx] = sr;
}

// ---------------- wave-cooperative aggregation, no stats pass ----------------
// Wave per dst. Lane owns features {2*lane, 2*lane+1} (one head, h = lane/(CH)).
// Per chunk of CH edges, lane-group q computes head q's unnormalized weight
// w = exp(lrelu(el+er)) exactly once; broadcast via shfl; denominators are
// per-group butterfly reductions. Softmax without max-subtraction (logits tiny).
// FIN==1: out = elu(sum/3 + resid + meanbias)   FIN==2: no ELU.
// resid may alias outp (same-thread read-then-write).
template <int H, int FIN>
__global__ __launch_bounds__(256) void aggr3_kernel(const int* __restrict__ row_ptr,
                                                    const int* __restrict__ csr_src,
                                                    const float* __restrict__ el,
                                                    const float* __restrict__ er,
                                                    const unsigned short* __restrict__ featb,
                                                    const float* __restrict__ resid,
                                                    const float* __restrict__ bias,
                                                    float* __restrict__ outp) {
    const int gid = blockIdx.x * 256 + threadIdx.x;
    const int d = gid >> 6;
    const int lane = gid & 63;
    if (d >= NN) return;
    const int f0 = lane * 2, f1 = f0 + 1;
    const int CH = (H == 4) ? 16 : 64;          // edges per chunk = 64/H
    const int myh = (H == 4) ? (lane >> 4) : 0; // head this lane computes/consumes
    const int sub = lane & (CH - 1);            // edge slot within chunk
    const int srcbase = lane & ~(CH - 1);       // shfl source group base
    float a0 = 0.f, a1 = 0.f;
    for (int r = 0; r < NR; ++r) {
        const int idx = r * NN + d;
        const int rs = row_ptr[idx];
        const int re = (idx + 1 < M3) ? row_ptr[idx + 1] : E3;
        const float erh = er[(size_t)r * NN * H + d * H + myh];
        const float* elr = el + (size_t)r * NN * H;
        const unsigned short* fb = featb + (size_t)r * NN * F;
        float den = 0.f, b0 = 0.f, b1 = 0.f;
        for (int base = rs; base < re; base += CH) {
            int cnt = re - base;
            if (cnt > CH) cnt = CH;
            int s_l = 0;
            float w_l = 0.f;
            if (sub < cnt) {
                s_l = csr_src[base + sub];
                w_l = __expf(lrelu(elr[s_l * H + myh] + erh));
            }
            den += w_l;
            for (int j = 0; j < cnt; ++j) {
                int srcl = j + srcbase;
                int sj = __shfl(s_l, srcl);
                float wj = __shfl(w_l, srcl);
                unsigned u = *(const unsigned*)(fb + (size_t)sj * F + f0);
                b0 += wj * bf2f((unsigned short)(u & 0xffff));
                b1 += wj * bf2f((unsigned short)(u >> 16));
            }
        }
#pragma unroll
        for (int off = CH >> 1; off; off >>= 1) den += __shfl_xor(den, off);
        float rd = 1.f / fmaxf(den, 1e-9f);
        a0 += b0 * rd;
        a1 += b1 * rd;
    }
    const float third = 1.f / 3.f;
    size_t o = (size_t)d * F;
    float bs0 = (bias[f0] + bias[F + f0] + bias[2 * F + f0]) * third;
    float bs1 = (bias[f1] + bias[F + f1] + bias[2 * F + f1]) * third;
    float2 rv = *(const float2*)&resid[o + f0];
    float v0 = a0 * third + rv.x + bs0;
    float v1 = a1 * third + rv.y + bs1;
    if (FIN == 1) {
        v0 = v0 > 0.f ? v0 : (__expf(v0) - 1.f);
        v1 = v1 > 0.f ? v1 : (__expf(v1) - 1.f);
    }
    *(float2*)&outp[o + f0] = make_float2(v0, v1);
}

extern "C" void kernel_launch(void* const* d_in, const int* in_sizes, int n_in,
                              void* d_out, int out_size, void* d_ws, size_t ws_size,
                              hipStream_t stream) {
    const float* x   = (const float*)d_in[0];
    const int* esrc  = (const int*)d_in[1];
    const int* edst  = (const int*)d_in[2];
    const float* W1  = (const float*)d_in[3];
    const float* b1  = (const float*)d_in[4];
    const float* al1 = (const float*)d_in[5];
    const float* ar1 = (const float*)d_in[6];
    const float* W2  = (const float*)d_in[7];
    const float* b2  = (const float*)d_in[8];
    const float* al2 = (const float*)d_in[9];
    const float* ar2 = (const float*)d_in[10];
    float* out = (float*)d_out;

    // workspace (~98.6 MB; proven-safe ws_size >= 108.8 MB). h1 lives in d_out.
    char* p = (char*)d_ws;
    unsigned short* featb = (unsigned short*)p;  p += (size_t)NR * NN * F * 2;  // 76.8 MB
    float* el    = (float*)p;                    p += (size_t)NR * NN * 4 * 4;  // 4.8 MB
    float* er    = (float*)p;                    p += (size_t)NR * NN * 4 * 4;
    int* row_ptr = (int*)p;                      p += (size_t)M3 * 4;
    int* alloc   = (int*)p;                      p += (size_t)M3 * 4;
    int* bsum    = (int*)p;                      p += (size_t)((NB1 + 63) & ~63) * 4;
    int* csr_src = (int*)p;                      p += (size_t)E3 * 4;           // 9.6 MB
    unsigned short* Bpack = (unsigned short*)p;  p += (size_t)6 * F * F * 2;
    float* h1 = out;

    dim3 b256(256);
    const int eg3 = (E3 + 255) / 256;
    const int gemm_grid = (NN + 127) / 128;
    const int g3h4 = (NR * NN * 4 + 255) / 256;
    const int g3h1 = (NR * NN * 1 + 255) / 256;
    const int agg = (NN * 64 + 255) / 256;

    // ---- build CSR by dst (shared by both layers) + pack weights
    hipMemsetAsync(row_ptr, 0, (size_t)M3 * 4, stream);
    packW_kernel<<<(6 * F * F + 255) / 256, b256, 0, stream>>>(W1, W2, Bpack);
    hist_kernel<<<eg3, b256, 0, stream>>>(edst, row_ptr);
    scan1_kernel<<<NB1, b256, 0, stream>>>(row_ptr, bsum, M3);
    scan2_kernel<<<1, b256, 0, stream>>>(bsum, NB1);
    scan3_kernel<<<NB1, b256, 0, stream>>>(row_ptr, alloc, bsum, M3);
    for (int pass = 0; pass < NPASS; ++pass)
        scatter_pass_kernel<<<eg3, b256, 0, stream>>>(esrc, edst, alloc, csr_src, pass * PW);

    // ---- layer 1: GATConv(128 -> 32, 4 heads) x3 relations, mean, +res +bias, ELU
    gemm_fused_kernel<<<gemm_grid, b256, 0, stream>>>(x, Bpack, featb);
    el_er_fused_kernel<4, 32><<<g3h4, b256, 0, stream>>>(featb, al1, ar1, el, er);
    aggr3_kernel<4, 1><<<agg, b256, 0, stream>>>(row_ptr, csr_src, el, er, featb, x, b1, h1);

    // ---- layer 2: GATConv(128 -> 128, 1 head) x3 relations, mean, +res +bias
    gemm_fused_kernel<<<gemm_grid, b256, 0, stream>>>(h1, Bpack + (size_t)3 * F * F, featb);
    el_er_fused_kernel<1, 128><<<g3h1, b256, 0, stream>>>(featb, al2, ar2, el, er);
    aggr3_kernel<1, 2><<<agg, b256, 0, stream>>>(row_ptr, csr_src, el, er, featb, h1, b2, out);
}

// Round 11
// 759.805 us; speedup vs baseline: 5.6381x; 1.0366x over previous
//
#include <hip/hip_runtime.h>
#include <hip/hip_bf16.h>

#define NN 100000
#define NE 800000
#define NR 3
#define F 128
#define M3 (NR * NN)               // 300000 CSR rows across relations
#define E3 (NR * NE)               // 2400000 edges total
#define NB1 ((M3 + 255) / 256)     // scan blocks
#define NPASS 8
#define PW ((NN + NPASS - 1) / NPASS)   // dst window per scatter pass

typedef __bf16 bf16x8 __attribute__((ext_vector_type(8)));
typedef float f32x4 __attribute__((ext_vector_type(4)));
typedef float f32x2 __attribute__((ext_vector_type(2)));

__device__ __forceinline__ float lrelu(float v) { return v >= 0.f ? v : 0.2f * v; }
__device__ __forceinline__ unsigned short f2bf(float f) {
    __hip_bfloat16 h = __float2bfloat16(f);
    unsigned short u;
    __builtin_memcpy(&u, &h, 2);
    return u;
}
// fp8 e4m3 helpers (gfx950 HW converters)
__device__ __forceinline__ unsigned char f2fp8(float v) {
    return (unsigned char)(__builtin_amdgcn_cvt_pk_fp8_f32(v, v, 0, false) & 0xff);
}
__device__ __forceinline__ f32x2 fp8x2_to_f32(unsigned short u) {
    return __builtin_amdgcn_cvt_pk_f32_fp8((int)u, false);
}

// ---------------- CSR build ----------------
__global__ __launch_bounds__(256) void hist_kernel(const int* __restrict__ edst,
                                                   int* __restrict__ counts) {
    int i = blockIdx.x * 256 + threadIdx.x;
    if (i >= E3) return;
    int r = i / NE;
    atomicAdd(&counts[r * NN + edst[i]], 1);
}

__global__ __launch_bounds__(256) void scan1_kernel(int* __restrict__ data,
                                                    int* __restrict__ bsum, int n) {
    __shared__ int lds[256];
    int i = blockIdx.x * 256 + threadIdx.x;
    int v = (i < n) ? data[i] : 0;
    lds[threadIdx.x] = v;
    __syncthreads();
#pragma unroll
    for (int off = 1; off < 256; off <<= 1) {
        int t = (threadIdx.x >= off) ? lds[threadIdx.x - off] : 0;
        __syncthreads();
        lds[threadIdx.x] += t;
        __syncthreads();
    }
    int incl = lds[threadIdx.x];
    if (i < n) data[i] = incl - v;
    if (threadIdx.x == 255) bsum[blockIdx.x] = incl;
}

__global__ __launch_bounds__(256) void scan2_kernel(int* __restrict__ bsum, int nb) {
    __shared__ int lds[256];
    int carry = 0;
    for (int base = 0; base < nb; base += 256) {
        int i = base + threadIdx.x;
        int v = (i < nb) ? bsum[i] : 0;
        lds[threadIdx.x] = v;
        __syncthreads();
#pragma unroll
        for (int off = 1; off < 256; off <<= 1) {
            int t = (threadIdx.x >= off) ? lds[threadIdx.x - off] : 0;
            __syncthreads();
            lds[threadIdx.x] += t;
            __syncthreads();
        }
        if (i < nb) bsum[i] = (lds[threadIdx.x] - v) + carry;
        int tot = lds[255];
        __syncthreads();
        carry += tot;
    }
}

__global__ __launch_bounds__(256) void scan3_kernel(int* __restrict__ row_ptr,
                                                    int* __restrict__ alloc,
                                                    const int* __restrict__ bsum, int n) {
    int i = blockIdx.x * 256 + threadIdx.x;
    if (i >= n) return;
    int v = row_ptr[i] + bsum[blockIdx.x];
    row_ptr[i] = v;
    alloc[i] = v;
}

// windowed scatter: active CSR write region ~1.2 MB -> lines fully filled
__global__ __launch_bounds__(256) void scatter_pass_kernel(const int* __restrict__ esrc,
                                                           const int* __restrict__ edst,
                                                           int* __restrict__ alloc,
                                                           int* __restrict__ csr_src,
                                                           int lo) {
    int i = blockIdx.x * 256 + threadIdx.x;
    if (i >= E3) return;
    int d = edst[i];
    if (d < lo || d >= lo + PW) return;
    int r = i / NE;
    int pos = atomicAdd(&alloc[r * NN + d], 1);
    csr_src[pos] = esrc[i];
}

// ---------------- pack W into MFMA B-fragment order (bf16) ----------------
__global__ __launch_bounds__(256) void packW_kernel(const float* __restrict__ W1,
                                                    const float* __restrict__ W2,
                                                    unsigned short* __restrict__ Bp) {
    int idx = blockIdx.x * 256 + threadIdx.x;
    if (idx >= 6 * 32 * 64 * 8) return;
    int j = idx & 7;
    int l = (idx >> 3) & 63;
    int tile = (idx >> 9) & 31;
    int m = idx >> 14;
    int ct = tile >> 2, kk = tile & 3;
    int col = ct * 16 + (l & 15);
    int k = kk * 32 + (l >> 4) * 8 + j;
    const float* W = (m < 3) ? (W1 + (size_t)m * (F * F)) : (W2 + (size_t)(m - 3) * (F * F));
    Bp[idx] = f2bf(W[k * F + col]);
}

// ---------------- fused MFMA GEMM: A staged once (bf16 LDS), 3 relations, fp8 out
__global__ __launch_bounds__(256) void gemm_fused_kernel(const float* __restrict__ A,
                                                         const unsigned short* __restrict__ Bp,
                                                         unsigned char* __restrict__ Y) {
    __shared__ __align__(16) unsigned short alds[128 * 128];  // 32 KB, XOR-swizzled
    const int t = threadIdx.x;
    const int row0 = blockIdx.x * 128;
#pragma unroll
    for (int it = 0; it < 16; ++it) {
        int g = it * 256 + t;
        int row = g >> 5, k4 = g & 31;
        int gr = row0 + row;
        float4 v;
        if (gr < NN) v = *(const float4*)(A + (size_t)gr * F + k4 * 4);
        else v = make_float4(0.f, 0.f, 0.f, 0.f);
        unsigned int lo = (unsigned)f2bf(v.x) | ((unsigned)f2bf(v.y) << 16);
        unsigned int hi = (unsigned)f2bf(v.z) | ((unsigned)f2bf(v.w) << 16);
        int k2 = k4 * 8;
        int byte = row * 256 + ((k2 & ~15) ^ ((row & 7) << 4)) + (k2 & 15);
        *(uint2*)((char*)alds + byte) = make_uint2(lo, hi);
    }
    __syncthreads();

    const int wv = t >> 6, lane = t & 63;
    const int lr = lane & 15;
    const int lkq = lane >> 4;
    for (int m = 0; m < NR; ++m) {
        const bf16x8* bp = (const bf16x8*)(Bp + (size_t)m * F * F);
        f32x4 acc[2][8];
#pragma unroll
        for (int rt = 0; rt < 2; ++rt)
#pragma unroll
            for (int ct = 0; ct < 8; ++ct) acc[rt][ct] = (f32x4){0.f, 0.f, 0.f, 0.f};
#pragma unroll
        for (int kk = 0; kk < 4; ++kk) {
            bf16x8 afr[2];
#pragma unroll
            for (int rt = 0; rt < 2; ++rt) {
                int row = wv * 32 + rt * 16 + lr;
                int k2 = kk * 64 + lkq * 16;
                int byte = row * 256 + (k2 ^ ((row & 7) << 4));
                afr[rt] = *(const bf16x8*)((const char*)alds + byte);
            }
#pragma unroll
            for (int ct = 0; ct < 8; ++ct) {
                bf16x8 b = bp[(ct * 4 + kk) * 64 + lane];
                acc[0][ct] = __builtin_amdgcn_mfma_f32_16x16x32_bf16(afr[0], b, acc[0][ct], 0, 0, 0);
                acc[1][ct] = __builtin_amdgcn_mfma_f32_16x16x32_bf16(afr[1], b, acc[1][ct], 0, 0, 0);
            }
        }
        unsigned char* Yp = Y + (size_t)m * NN * F;
        const int crow = lkq * 4;
#pragma unroll
        for (int rt = 0; rt < 2; ++rt)
#pragma unroll
            for (int i = 0; i < 4; ++i) {
                int rr = row0 + wv * 32 + rt * 16 + crow + i;
                if (rr < NN) {
#pragma unroll
                    for (int ct = 0; ct < 8; ++ct)
                        Yp[(size_t)rr * F + ct * 16 + lr] = f2fp8(acc[rt][ct][i]);
                }
            }
    }
}

// ---------------- el/er from fp8 feat, all 3 relations; el[r*NN*H + n*H + h]
template <int H, int D>
__global__ __launch_bounds__(256) void el_er_fused_kernel(const unsigned char* __restrict__ featb,
                                                          const float* __restrict__ al,
                                                          const float* __restrict__ ar,
                                                          float* __restrict__ el,
                                                          float* __restrict__ er) {
    int idx = blockIdx.x * 256 + threadIdx.x;
    if (idx >= NR * NN * H) return;
    int r = idx / (NN * H);
    int w = idx - r * (NN * H);
    int h = w & (H - 1);
    const unsigned* fp = (const unsigned*)(featb + (size_t)r * NN * F + (size_t)w * D);
    const float4* ap = (const float4*)(al + r * F + h * D);
    const float4* bp = (const float4*)(ar + r * F + h * D);
    float sl = 0.f, sr = 0.f;
#pragma unroll
    for (int q = 0; q < D / 4; ++q) {
        unsigned u = fp[q];
        f32x2 d0 = fp8x2_to_f32((unsigned short)(u & 0xffff));
        f32x2 d1 = fp8x2_to_f32((unsigned short)(u >> 16));
        float4 a = ap[q], b = bp[q];
        sl += d0.x * a.x + d0.y * a.y + d1.x * a.z + d1.y * a.w;
        sr += d0.x * b.x + d0.y * b.y + d1.x * b.z + d1.y * b.w;
    }
    el[idx] = sl;
    er[idx] = sr;
}

// ---------------- wave-cooperative aggregation (fp8 gather, 1 line/row) ------
// Wave per dst. Lane owns features {2*lane, 2*lane+1} (head h = lane/CH).
// Per chunk of CH edges, lane-group q computes head q's weight once; shfl
// broadcast; per-group butterfly for denominators. No max-subtraction.
template <int H, int FIN>
__global__ __launch_bounds__(256) void aggr3_kernel(const int* __restrict__ row_ptr,
                                                    const int* __restrict__ csr_src,
                                                    const float* __restrict__ el,
                                                    const float* __restrict__ er,
                                                    const unsigned char* __restrict__ featb,
                                                    const float* __restrict__ resid,
                                                    const float* __restrict__ bias,
                                                    float* __restrict__ outp) {
    const int gid = blockIdx.x * 256 + threadIdx.x;
    const int d = gid >> 6;
    const int lane = gid & 63;
    if (d >= NN) return;
    const int f0 = lane * 2, f1 = f0 + 1;
    const int CH = (H == 4) ? 16 : 64;
    const int myh = (H == 4) ? (lane >> 4) : 0;
    const int sub = lane & (CH - 1);
    const int srcbase = lane & ~(CH - 1);
    float a0 = 0.f, a1 = 0.f;
    for (int r = 0; r < NR; ++r) {
        const int idx = r * NN + d;
        const int rs = row_ptr[idx];
        const int re = (idx + 1 < M3) ? row_ptr[idx + 1] : E3;
        const float erh = er[(size_t)r * NN * H + d * H + myh];
        const float* elr = el + (size_t)r * NN * H;
        const unsigned char* fb = featb + (size_t)r * NN * F;
        float den = 0.f, b0 = 0.f, b1 = 0.f;
        for (int base = rs; base < re; base += CH) {
            int cnt = re - base;
            if (cnt > CH) cnt = CH;
            int s_l = 0;
            float w_l = 0.f;
            if (sub < cnt) {
                s_l = csr_src[base + sub];
                w_l = __expf(lrelu(elr[s_l * H + myh] + erh));
            }
            den += w_l;
            for (int j = 0; j < cnt; ++j) {
                int srcl = j + srcbase;
                int sj = __shfl(s_l, srcl);
                float wj = __shfl(w_l, srcl);
                unsigned short u = *(const unsigned short*)(fb + (size_t)sj * F + f0);
                f32x2 dv = fp8x2_to_f32(u);
                b0 += wj * dv.x;
                b1 += wj * dv.y;
            }
        }
#pragma unroll
        for (int off = CH >> 1; off; off >>= 1) den += __shfl_xor(den, off);
        float rd = 1.f / fmaxf(den, 1e-9f);
        a0 += b0 * rd;
        a1 += b1 * rd;
    }
    const float third = 1.f / 3.f;
    size_t o = (size_t)d * F;
    float bs0 = (bias[f0] + bias[F + f0] + bias[2 * F + f0]) * third;
    float bs1 = (bias[f1] + bias[F + f1] + bias[2 * F + f1]) * third;
    float2 rv = *(const float2*)&resid[o + f0];
    float v0 = a0 * third + rv.x + bs0;
    float v1 = a1 * third + rv.y + bs1;
    if (FIN == 1) {
        v0 = v0 > 0.f ? v0 : (__expf(v0) - 1.f);
        v1 = v1 > 0.f ? v1 : (__expf(v1) - 1.f);
    }
    *(float2*)&outp[o + f0] = make_float2(v0, v1);
}

extern "C" void kernel_launch(void* const* d_in, const int* in_sizes, int n_in,
                              void* d_out, int out_size, void* d_ws, size_t ws_size,
                              hipStream_t stream) {
    const float* x   = (const float*)d_in[0];
    const int* esrc  = (const int*)d_in[1];
    const int* edst  = (const int*)d_in[2];
    const float* W1  = (const float*)d_in[3];
    const float* b1  = (const float*)d_in[4];
    const float* al1 = (const float*)d_in[5];
    const float* ar1 = (const float*)d_in[6];
    const float* W2  = (const float*)d_in[7];
    const float* b2  = (const float*)d_in[8];
    const float* al2 = (const float*)d_in[9];
    const float* ar2 = (const float*)d_in[10];
    float* out = (float*)d_out;

    // workspace (~60 MB; proven-safe >= 108.8 MB). h1 lives in d_out.
    char* p = (char*)d_ws;
    unsigned char* featb = (unsigned char*)p;    p += (size_t)NR * NN * F;      // 38.4 MB
    float* el    = (float*)p;                    p += (size_t)NR * NN * 4 * 4;  // 4.8 MB
    float* er    = (float*)p;                    p += (size_t)NR * NN * 4 * 4;
    int* row_ptr = (int*)p;                      p += (size_t)M3 * 4;
    int* alloc   = (int*)p;                      p += (size_t)M3 * 4;
    int* bsum    = (int*)p;                      p += (size_t)((NB1 + 63) & ~63) * 4;
    int* csr_src = (int*)p;                      p += (size_t)E3 * 4;           // 9.6 MB
    unsigned short* Bpack = (unsigned short*)p;  p += (size_t)6 * F * F * 2;
    float* h1 = out;

    dim3 b256(256);
    const int eg3 = (E3 + 255) / 256;
    const int gemm_grid = (NN + 127) / 128;
    const int g3h4 = (NR * NN * 4 + 255) / 256;
    const int g3h1 = (NR * NN * 1 + 255) / 256;
    const int agg = (NN * 64 + 255) / 256;

    // ---- build CSR by dst (shared by both layers) + pack weights
    hipMemsetAsync(row_ptr, 0, (size_t)M3 * 4, stream);
    packW_kernel<<<(6 * F * F + 255) / 256, b256, 0, stream>>>(W1, W2, Bpack);
    hist_kernel<<<eg3, b256, 0, stream>>>(edst, row_ptr);
    scan1_kernel<<<NB1, b256, 0, stream>>>(row_ptr, bsum, M3);
    scan2_kernel<<<1, b256, 0, stream>>>(bsum, NB1);
    scan3_kernel<<<NB1, b256, 0, stream>>>(row_ptr, alloc, bsum, M3);
    for (int pass = 0; pass < NPASS; ++pass)
        scatter_pass_kernel<<<eg3, b256, 0, stream>>>(esrc, edst, alloc, csr_src, pass * PW);

    // ---- layer 1: GATConv(128 -> 32, 4 heads) x3 relations, mean, +res +bias, ELU
    gemm_fused_kernel<<<gemm_grid, b256, 0, stream>>>(x, Bpack, featb);
    el_er_fused_kernel<4, 32><<<g3h4, b256, 0, stream>>>(featb, al1, ar1, el, er);
    aggr3_kernel<4, 1><<<agg, b256, 0, stream>>>(row_ptr, csr_src, el, er, featb, x, b1, h1);

    // ---- layer 2: GATConv(128 -> 128, 1 head) x3 relations, mean, +res +bias
    gemm_fused_kernel<<<gemm_grid, b256, 0, stream>>>(h1, Bpack + (size_t)3 * F * F, featb);
    el_er_fused_kernel<1, 128><<<g3h1, b256, 0, stream>>>(featb, al2, ar2, el, er);
    aggr3_kernel<1, 2><<<agg, b256, 0, stream>>>(row_ptr, csr_src, el, er, featb, h1, b2, out);
}

// Round 12
// 624.365 us; speedup vs baseline: 6.8611x; 1.2169x over previous
//
#include <hip/hip_runtime.h>
#include <hip/hip_bf16.h>

#define NN 100000
#define NE 800000
#define NR 3
#define F 128
#define M3 (NR * NN)               // 300000 CSR rows across relations
#define E3 (NR * NE)               // 2400000 edges total
#define NB1 ((M3 + 255) / 256)     // scan blocks
#define NPASS 4
#define PW ((NN + NPASS - 1) / NPASS)   // dst window per scatter pass

typedef __bf16 bf16x8 __attribute__((ext_vector_type(8)));
typedef float f32x4 __attribute__((ext_vector_type(4)));
typedef float f32x2 __attribute__((ext_vector_type(2)));

__device__ __forceinline__ float lrelu(float v) { return v >= 0.f ? v : 0.2f * v; }
__device__ __forceinline__ unsigned short f2bf(float f) {
    __hip_bfloat16 h = __float2bfloat16(f);
    unsigned short u;
    __builtin_memcpy(&u, &h, 2);
    return u;
}
// fp8 e4m3 helpers (gfx950 HW converters)
__device__ __forceinline__ unsigned char f2fp8(float v) {
    return (unsigned char)(__builtin_amdgcn_cvt_pk_fp8_f32(v, v, 0, false) & 0xff);
}
__device__ __forceinline__ f32x2 fp8x2_to_f32(unsigned short u) {
    return __builtin_amdgcn_cvt_pk_f32_fp8((int)u, false);
}

// ---------------- CSR build ----------------
__global__ __launch_bounds__(256) void hist_kernel(const int* __restrict__ edst,
                                                   int* __restrict__ counts) {
    int i = blockIdx.x * 256 + threadIdx.x;
    if (i >= E3) return;
    int r = i / NE;
    atomicAdd(&counts[r * NN + edst[i]], 1);
}

__global__ __launch_bounds__(256) void scan1_kernel(int* __restrict__ data,
                                                    int* __restrict__ bsum, int n) {
    __shared__ int lds[256];
    int i = blockIdx.x * 256 + threadIdx.x;
    int v = (i < n) ? data[i] : 0;
    lds[threadIdx.x] = v;
    __syncthreads();
#pragma unroll
    for (int off = 1; off < 256; off <<= 1) {
        int t = (threadIdx.x >= off) ? lds[threadIdx.x - off] : 0;
        __syncthreads();
        lds[threadIdx.x] += t;
        __syncthreads();
    }
    int incl = lds[threadIdx.x];
    if (i < n) data[i] = incl - v;
    if (threadIdx.x == 255) bsum[blockIdx.x] = incl;
}

__global__ __launch_bounds__(256) void scan2_kernel(int* __restrict__ bsum, int nb) {
    __shared__ int lds[256];
    int carry = 0;
    for (int base = 0; base < nb; base += 256) {
        int i = base + threadIdx.x;
        int v = (i < nb) ? bsum[i] : 0;
        lds[threadIdx.x] = v;
        __syncthreads();
#pragma unroll
        for (int off = 1; off < 256; off <<= 1) {
            int t = (threadIdx.x >= off) ? lds[threadIdx.x - off] : 0;
            __syncthreads();
            lds[threadIdx.x] += t;
            __syncthreads();
        }
        if (i < nb) bsum[i] = (lds[threadIdx.x] - v) + carry;
        int tot = lds[255];
        __syncthreads();
        carry += tot;
    }
}

__global__ __launch_bounds__(256) void scan3_kernel(int* __restrict__ row_ptr,
                                                    int* __restrict__ alloc,
                                                    const int* __restrict__ bsum, int n) {
    int i = blockIdx.x * 256 + threadIdx.x;
    if (i >= n) return;
    int v = row_ptr[i] + bsum[blockIdx.x];
    row_ptr[i] = v;
    alloc[i] = v;
}

// windowed scatter: active CSR write region ~2.4 MB -> lines mostly filled
__global__ __launch_bounds__(256) void scatter_pass_kernel(const int* __restrict__ esrc,
                                                           const int* __restrict__ edst,
                                                           int* __restrict__ alloc,
                                                           int* __restrict__ csr_src,
                                                           int lo) {
    int i = blockIdx.x * 256 + threadIdx.x;
    if (i >= E3) return;
    int d = edst[i];
    if (d < lo || d >= lo + PW) return;
    int r = i / NE;
    int pos = atomicAdd(&alloc[r * NN + d], 1);
    csr_src[pos] = esrc[i];
}

// ---------------- pack W into MFMA B-fragment order (bf16) ----------------
__global__ __launch_bounds__(256) void packW_kernel(const float* __restrict__ W1,
                                                    const float* __restrict__ W2,
                                                    unsigned short* __restrict__ Bp) {
    int idx = blockIdx.x * 256 + threadIdx.x;
    if (idx >= 6 * 32 * 64 * 8) return;
    int j = idx & 7;
    int l = (idx >> 3) & 63;
    int tile = (idx >> 9) & 31;
    int m = idx >> 14;
    int ct = tile >> 2, kk = tile & 3;
    int col = ct * 16 + (l & 15);
    int k = kk * 32 + (l >> 4) * 8 + j;
    const float* W = (m < 3) ? (W1 + (size_t)m * (F * F)) : (W2 + (size_t)(m - 3) * (F * F));
    Bp[idx] = f2bf(W[k * F + col]);
}

// ---------------- fused MFMA GEMM: A staged once (bf16 LDS), 3 relations, fp8 out
__global__ __launch_bounds__(256) void gemm_fused_kernel(const float* __restrict__ A,
                                                         const unsigned short* __restrict__ Bp,
                                                         unsigned char* __restrict__ Y) {
    __shared__ __align__(16) unsigned short alds[128 * 128];  // 32 KB, XOR-swizzled
    const int t = threadIdx.x;
    const int row0 = blockIdx.x * 128;
#pragma unroll
    for (int it = 0; it < 16; ++it) {
        int g = it * 256 + t;
        int row = g >> 5, k4 = g & 31;
        int gr = row0 + row;
        float4 v;
        if (gr < NN) v = *(const float4*)(A + (size_t)gr * F + k4 * 4);
        else v = make_float4(0.f, 0.f, 0.f, 0.f);
        unsigned int lo = (unsigned)f2bf(v.x) | ((unsigned)f2bf(v.y) << 16);
        unsigned int hi = (unsigned)f2bf(v.z) | ((unsigned)f2bf(v.w) << 16);
        int k2 = k4 * 8;
        int byte = row * 256 + ((k2 & ~15) ^ ((row & 7) << 4)) + (k2 & 15);
        *(uint2*)((char*)alds + byte) = make_uint2(lo, hi);
    }
    __syncthreads();

    const int wv = t >> 6, lane = t & 63;
    const int lr = lane & 15;
    const int lkq = lane >> 4;
    for (int m = 0; m < NR; ++m) {
        const bf16x8* bp = (const bf16x8*)(Bp + (size_t)m * F * F);
        f32x4 acc[2][8];
#pragma unroll
        for (int rt = 0; rt < 2; ++rt)
#pragma unroll
            for (int ct = 0; ct < 8; ++ct) acc[rt][ct] = (f32x4){0.f, 0.f, 0.f, 0.f};
#pragma unroll
        for (int kk = 0; kk < 4; ++kk) {
            bf16x8 afr[2];
#pragma unroll
            for (int rt = 0; rt < 2; ++rt) {
                int row = wv * 32 + rt * 16 + lr;
                int k2 = kk * 64 + lkq * 16;
                int byte = row * 256 + (k2 ^ ((row & 7) << 4));
                afr[rt] = *(const bf16x8*)((const char*)alds + byte);
            }
#pragma unroll
            for (int ct = 0; ct < 8; ++ct) {
                bf16x8 b = bp[(ct * 4 + kk) * 64 + lane];
                acc[0][ct] = __builtin_amdgcn_mfma_f32_16x16x32_bf16(afr[0], b, acc[0][ct], 0, 0, 0);
                acc[1][ct] = __builtin_amdgcn_mfma_f32_16x16x32_bf16(afr[1], b, acc[1][ct], 0, 0, 0);
            }
        }
        unsigned char* Yp = Y + (size_t)m * NN * F;
        const int crow = lkq * 4;
#pragma unroll
        for (int rt = 0; rt < 2; ++rt)
#pragma unroll
            for (int i = 0; i < 4; ++i) {
                int rr = row0 + wv * 32 + rt * 16 + crow + i;
                if (rr < NN) {
#pragma unroll
                    for (int ct = 0; ct < 8; ++ct)
                        Yp[(size_t)rr * F + ct * 16 + lr] = f2fp8(acc[rt][ct][i]);
                }
            }
    }
}

// ---------------- el/er from fp8 feat, all 3 relations; el[r*NN*H + n*H + h]
template <int H, int D>
__global__ __launch_bounds__(256) void el_er_fused_kernel(const unsigned char* __restrict__ featb,
                                                          const float* __restrict__ al,
                                                          const float* __restrict__ ar,
                                                          float* __restrict__ el,
                                                          float* __restrict__ er) {
    int idx = blockIdx.x * 256 + threadIdx.x;
    if (idx >= NR * NN * H) return;
    int r = idx / (NN * H);
    int w = idx - r * (NN * H);
    int h = w & (H - 1);
    const unsigned* fp = (const unsigned*)(featb + (size_t)r * NN * F + (size_t)w * D);
    const float4* ap = (const float4*)(al + r * F + h * D);
    const float4* bp = (const float4*)(ar + r * F + h * D);
    float sl = 0.f, sr = 0.f;
#pragma unroll
    for (int q = 0; q < D / 4; ++q) {
        unsigned u = fp[q];
        f32x2 d0 = fp8x2_to_f32((unsigned short)(u & 0xffff));
        f32x2 d1 = fp8x2_to_f32((unsigned short)(u >> 16));
        float4 a = ap[q], b = bp[q];
        sl += d0.x * a.x + d0.y * a.y + d1.x * a.z + d1.y * a.w;
        sr += d0.x * b.x + d0.y * b.y + d1.x * b.z + d1.y * b.w;
    }
    el[idx] = sl;
    er[idx] = sr;
}

// ---------------- wave-cooperative aggregation, 8-deep batched gather -------
// Wave per dst. Lane owns features {2*lane, 2*lane+1} (head h = lane/CH).
// Per chunk of CH edges: lane-group computes weights once; then edges are
// consumed in batches of 8 — 8 independent row-slice loads issued before any
// decode/FMA, giving 8 gathers in flight per wave (latency hiding).
template <int H, int FIN>
__global__ __launch_bounds__(256) void aggr3_kernel(const int* __restrict__ row_ptr,
                                                    const int* __restrict__ csr_src,
                                                    const float* __restrict__ el,
                                                    const float* __restrict__ er,
                                                    const unsigned char* __restrict__ featb,
                                                    const float* __restrict__ resid,
                                                    const float* __restrict__ bias,
                                                    float* __restrict__ outp) {
    const int gid = blockIdx.x * 256 + threadIdx.x;
    const int d = gid >> 6;
    const int lane = gid & 63;
    if (d >= NN) return;
    const int f0 = lane * 2;
    const int CH = (H == 4) ? 16 : 64;
    const int myh = (H == 4) ? (lane >> 4) : 0;
    const int sub = lane & (CH - 1);
    const int srcbase = lane & ~(CH - 1);
    float a0 = 0.f, a1 = 0.f;
    for (int r = 0; r < NR; ++r) {
        const int idx = r * NN + d;
        const int rs = row_ptr[idx];
        const int re = (idx + 1 < M3) ? row_ptr[idx + 1] : E3;
        const float erh = er[(size_t)r * NN * H + d * H + myh];
        const float* elr = el + (size_t)r * NN * H;
        const unsigned char* fb = featb + (size_t)r * NN * F;
        float den = 0.f, b0 = 0.f, b1 = 0.f;
        for (int base = rs; base < re; base += CH) {
            int cnt = re - base;
            if (cnt > CH) cnt = CH;
            int s_l = 0;
            float w_l = 0.f;
            if (sub < cnt) {
                s_l = csr_src[base + sub];
                w_l = __expf(lrelu(elr[s_l * H + myh] + erh));
            }
            den += w_l;
            for (int j = 0; j < cnt; j += 8) {
                int sj[8];
                float wj[8];
#pragma unroll
                for (int q = 0; q < 8; ++q) {
                    int e = j + q;
                    int ec = e < cnt ? e : cnt - 1;     // wave-uniform clamp
                    sj[q] = __shfl(s_l, srcbase + ec);
                    float w = __shfl(w_l, srcbase + ec);
                    wj[q] = (e < cnt) ? w : 0.f;
                }
                unsigned short u[8];
#pragma unroll
                for (int q = 0; q < 8; ++q)
                    u[q] = *(const unsigned short*)(fb + (size_t)sj[q] * F + f0);
#pragma unroll
                for (int q = 0; q < 8; ++q) {
                    f32x2 dv = fp8x2_to_f32(u[q]);
                    b0 += wj[q] * dv.x;
                    b1 += wj[q] * dv.y;
                }
            }
        }
#pragma unroll
        for (int off = CH >> 1; off; off >>= 1) den += __shfl_xor(den, off);
        float rd = 1.f / fmaxf(den, 1e-9f);
        a0 += b0 * rd;
        a1 += b1 * rd;
    }
    const float third = 1.f / 3.f;
    size_t o = (size_t)d * F;
    const int f1 = f0 + 1;
    float bs0 = (bias[f0] + bias[F + f0] + bias[2 * F + f0]) * third;
    float bs1 = (bias[f1] + bias[F + f1] + bias[2 * F + f1]) * third;
    float2 rv = *(const float2*)&resid[o + f0];
    float v0 = a0 * third + rv.x + bs0;
    float v1 = a1 * third + rv.y + bs1;
    if (FIN == 1) {
        v0 = v0 > 0.f ? v0 : (__expf(v0) - 1.f);
        v1 = v1 > 0.f ? v1 : (__expf(v1) - 1.f);
    }
    *(float2*)&outp[o + f0] = make_float2(v0, v1);
}

extern "C" void kernel_launch(void* const* d_in, const int* in_sizes, int n_in,
                              void* d_out, int out_size, void* d_ws, size_t ws_size,
                              hipStream_t stream) {
    const float* x   = (const float*)d_in[0];
    const int* esrc  = (const int*)d_in[1];
    const int* edst  = (const int*)d_in[2];
    const float* W1  = (const float*)d_in[3];
    const float* b1  = (const float*)d_in[4];
    const float* al1 = (const float*)d_in[5];
    const float* ar1 = (const float*)d_in[6];
    const float* W2  = (const float*)d_in[7];
    const float* b2  = (const float*)d_in[8];
    const float* al2 = (const float*)d_in[9];
    const float* ar2 = (const float*)d_in[10];
    float* out = (float*)d_out;

    // workspace (~60 MB; proven-safe >= 108.8 MB). h1 lives in d_out.
    char* p = (char*)d_ws;
    unsigned char* featb = (unsigned char*)p;    p += (size_t)NR * NN * F;      // 38.4 MB
    float* el    = (float*)p;                    p += (size_t)NR * NN * 4 * 4;  // 4.8 MB
    float* er    = (float*)p;                    p += (size_t)NR * NN * 4 * 4;
    int* row_ptr = (int*)p;                      p += (size_t)M3 * 4;
    int* alloc   = (int*)p;                      p += (size_t)M3 * 4;
    int* bsum    = (int*)p;                      p += (size_t)((NB1 + 63) & ~63) * 4;
    int* csr_src = (int*)p;                      p += (size_t)E3 * 4;           // 9.6 MB
    unsigned short* Bpack = (unsigned short*)p;  p += (size_t)6 * F * F * 2;
    float* h1 = out;

    dim3 b256(256);
    const int eg3 = (E3 + 255) / 256;
    const int gemm_grid = (NN + 127) / 128;
    const int g3h4 = (NR * NN * 4 + 255) / 256;
    const int g3h1 = (NR * NN * 1 + 255) / 256;
    const int agg = (NN * 64 + 255) / 256;

    // ---- build CSR by dst (shared by both layers) + pack weights
    hipMemsetAsync(row_ptr, 0, (size_t)M3 * 4, stream);
    packW_kernel<<<(6 * F * F + 255) / 256, b256, 0, stream>>>(W1, W2, Bpack);
    hist_kernel<<<eg3, b256, 0, stream>>>(edst, row_ptr);
    scan1_kernel<<<NB1, b256, 0, stream>>>(row_ptr, bsum, M3);
    scan2_kernel<<<1, b256, 0, stream>>>(bsum, NB1);
    scan3_kernel<<<NB1, b256, 0, stream>>>(row_ptr, alloc, bsum, M3);
    for (int pass = 0; pass < NPASS; ++pass)
        scatter_pass_kernel<<<eg3, b256, 0, stream>>>(esrc, edst, alloc, csr_src, pass * PW);

    // ---- layer 1: GATConv(128 -> 32, 4 heads) x3 relations, mean, +res +bias, ELU
    gemm_fused_kernel<<<gemm_grid, b256, 0, stream>>>(x, Bpack, featb);
    el_er_fused_kernel<4, 32><<<g3h4, b256, 0, stream>>>(featb, al1, ar1, el, er);
    aggr3_kernel<4, 1><<<agg, b256, 0, stream>>>(row_ptr, csr_src, el, er, featb, x, b1, h1);

    // ---- layer 2: GATConv(128 -> 128, 1 head) x3 relations, mean, +res +bias
    gemm_fused_kernel<<<gemm_grid, b256, 0, stream>>>(h1, Bpack + (size_t)3 * F * F, featb);
    el_er_fused_kernel<1, 128><<<g3h1, b256, 0, stream>>>(featb, al2, ar2, el, er);
    aggr3_kernel<1, 2><<<agg, b256, 0, stream>>>(row_ptr, csr_src, el, er, featb, h1, b2, out);
}

// Round 13
// 595.219 us; speedup vs baseline: 7.1971x; 1.0490x over previous
//
#include <hip/hip_runtime.h>
#include <hip/hip_bf16.h>

#define NN 100000
#define NE 800000
#define NR 3
#define F 128
#define M3 (NR * NN)               // 300000 CSR rows across relations
#define E3 (NR * NE)               // 2400000 edges total
#define NB1 ((M3 + 255) / 256)     // scan blocks
#define NPASS 4
#define PW ((NN + NPASS - 1) / NPASS)   // dst window per scatter pass

typedef __bf16 bf16x8 __attribute__((ext_vector_type(8)));
typedef float f32x4 __attribute__((ext_vector_type(4)));
typedef float f32x2 __attribute__((ext_vector_type(2)));

__device__ __forceinline__ float lrelu(float v) { return v >= 0.f ? v : 0.2f * v; }
__device__ __forceinline__ unsigned short f2bf(float f) {
    __hip_bfloat16 h = __float2bfloat16(f);
    unsigned short u;
    __builtin_memcpy(&u, &h, 2);
    return u;
}
// fp8 e4m3 helpers (gfx950 HW converters)
__device__ __forceinline__ unsigned char f2fp8(float v) {
    return (unsigned char)(__builtin_amdgcn_cvt_pk_fp8_f32(v, v, 0, false) & 0xff);
}
__device__ __forceinline__ f32x2 fp8x2_to_f32(unsigned short u) {
    return __builtin_amdgcn_cvt_pk_f32_fp8((int)u, false);
}

// ---------------- CSR build ----------------
__global__ __launch_bounds__(256) void hist_kernel(const int* __restrict__ edst,
                                                   int* __restrict__ counts) {
    int i = blockIdx.x * 256 + threadIdx.x;
    if (i >= E3) return;
    int r = i / NE;
    atomicAdd(&counts[r * NN + edst[i]], 1);
}

__global__ __launch_bounds__(256) void scan1_kernel(int* __restrict__ data,
                                                    int* __restrict__ bsum, int n) {
    __shared__ int lds[256];
    int i = blockIdx.x * 256 + threadIdx.x;
    int v = (i < n) ? data[i] : 0;
    lds[threadIdx.x] = v;
    __syncthreads();
#pragma unroll
    for (int off = 1; off < 256; off <<= 1) {
        int t = (threadIdx.x >= off) ? lds[threadIdx.x - off] : 0;
        __syncthreads();
        lds[threadIdx.x] += t;
        __syncthreads();
    }
    int incl = lds[threadIdx.x];
    if (i < n) data[i] = incl - v;
    if (threadIdx.x == 255) bsum[blockIdx.x] = incl;
}

__global__ __launch_bounds__(256) void scan2_kernel(int* __restrict__ bsum, int nb) {
    __shared__ int lds[256];
    int carry = 0;
    for (int base = 0; base < nb; base += 256) {
        int i = base + threadIdx.x;
        int v = (i < nb) ? bsum[i] : 0;
        lds[threadIdx.x] = v;
        __syncthreads();
#pragma unroll
        for (int off = 1; off < 256; off <<= 1) {
            int t = (threadIdx.x >= off) ? lds[threadIdx.x - off] : 0;
            __syncthreads();
            lds[threadIdx.x] += t;
            __syncthreads();
        }
        if (i < nb) bsum[i] = (lds[threadIdx.x] - v) + carry;
        int tot = lds[255];
        __syncthreads();
        carry += tot;
    }
}

__global__ __launch_bounds__(256) void scan3_kernel(int* __restrict__ row_ptr,
                                                    int* __restrict__ alloc,
                                                    const int* __restrict__ bsum, int n) {
    int i = blockIdx.x * 256 + threadIdx.x;
    if (i >= n) return;
    int v = row_ptr[i] + bsum[blockIdx.x];
    row_ptr[i] = v;
    alloc[i] = v;
}

// windowed scatter: active CSR write region ~2.4 MB -> lines mostly filled
__global__ __launch_bounds__(256) void scatter_pass_kernel(const int* __restrict__ esrc,
                                                           const int* __restrict__ edst,
                                                           int* __restrict__ alloc,
                                                           int* __restrict__ csr_src,
                                                           int lo) {
    int i = blockIdx.x * 256 + threadIdx.x;
    if (i >= E3) return;
    int d = edst[i];
    if (d < lo || d >= lo + PW) return;
    int r = i / NE;
    int pos = atomicAdd(&alloc[r * NN + d], 1);
    csr_src[pos] = esrc[i];
}

// ---------------- pack W into MFMA B-fragment order (bf16) ----------------
__global__ __launch_bounds__(256) void packW_kernel(const float* __restrict__ W1,
                                                    const float* __restrict__ W2,
                                                    unsigned short* __restrict__ Bp) {
    int idx = blockIdx.x * 256 + threadIdx.x;
    if (idx >= 6 * 32 * 64 * 8) return;
    int j = idx & 7;
    int l = (idx >> 3) & 63;
    int tile = (idx >> 9) & 31;
    int m = idx >> 14;
    int ct = tile >> 2, kk = tile & 3;
    int col = ct * 16 + (l & 15);
    int k = kk * 32 + (l >> 4) * 8 + j;
    const float* W = (m < 3) ? (W1 + (size_t)m * (F * F)) : (W2 + (size_t)(m - 3) * (F * F));
    Bp[idx] = f2bf(W[k * F + col]);
}

// ---------------- fused MFMA GEMM: A staged once (bf16 LDS), 3 relations, fp8 out
__global__ __launch_bounds__(256) void gemm_fused_kernel(const float* __restrict__ A,
                                                         const unsigned short* __restrict__ Bp,
                                                         unsigned char* __restrict__ Y) {
    __shared__ __align__(16) unsigned short alds[128 * 128];  // 32 KB, XOR-swizzled
    const int t = threadIdx.x;
    const int row0 = blockIdx.x * 128;
#pragma unroll
    for (int it = 0; it < 16; ++it) {
        int g = it * 256 + t;
        int row = g >> 5, k4 = g & 31;
        int gr = row0 + row;
        float4 v;
        if (gr < NN) v = *(const float4*)(A + (size_t)gr * F + k4 * 4);
        else v = make_float4(0.f, 0.f, 0.f, 0.f);
        unsigned int lo = (unsigned)f2bf(v.x) | ((unsigned)f2bf(v.y) << 16);
        unsigned int hi = (unsigned)f2bf(v.z) | ((unsigned)f2bf(v.w) << 16);
        int k2 = k4 * 8;
        int byte = row * 256 + ((k2 & ~15) ^ ((row & 7) << 4)) + (k2 & 15);
        *(uint2*)((char*)alds + byte) = make_uint2(lo, hi);
    }
    __syncthreads();

    const int wv = t >> 6, lane = t & 63;
    const int lr = lane & 15;
    const int lkq = lane >> 4;
    for (int m = 0; m < NR; ++m) {
        const bf16x8* bp = (const bf16x8*)(Bp + (size_t)m * F * F);
        f32x4 acc[2][8];
#pragma unroll
        for (int rt = 0; rt < 2; ++rt)
#pragma unroll
            for (int ct = 0; ct < 8; ++ct) acc[rt][ct] = (f32x4){0.f, 0.f, 0.f, 0.f};
#pragma unroll
        for (int kk = 0; kk < 4; ++kk) {
            bf16x8 afr[2];
#pragma unroll
            for (int rt = 0; rt < 2; ++rt) {
                int row = wv * 32 + rt * 16 + lr;
                int k2 = kk * 64 + lkq * 16;
                int byte = row * 256 + (k2 ^ ((row & 7) << 4));
                afr[rt] = *(const bf16x8*)((const char*)alds + byte);
            }
#pragma unroll
            for (int ct = 0; ct < 8; ++ct) {
                bf16x8 b = bp[(ct * 4 + kk) * 64 + lane];
                acc[0][ct] = __builtin_amdgcn_mfma_f32_16x16x32_bf16(afr[0], b, acc[0][ct], 0, 0, 0);
                acc[1][ct] = __builtin_amdgcn_mfma_f32_16x16x32_bf16(afr[1], b, acc[1][ct], 0, 0, 0);
            }
        }
        unsigned char* Yp = Y + (size_t)m * NN * F;
        const int crow = lkq * 4;
#pragma unroll
        for (int rt = 0; rt < 2; ++rt)
#pragma unroll
            for (int i = 0; i < 4; ++i) {
                int rr = row0 + wv * 32 + rt * 16 + crow + i;
                if (rr < NN) {
#pragma unroll
                    for (int ct = 0; ct < 8; ++ct)
                        Yp[(size_t)rr * F + ct * 16 + lr] = f2fp8(acc[rt][ct][i]);
                }
            }
    }
}

// ---------------- el/er from fp8 feat, all 3 relations; el[r*NN*H + n*H + h]
template <int H, int D>
__global__ __launch_bounds__(256) void el_er_fused_kernel(const unsigned char* __restrict__ featb,
                                                          const float* __restrict__ al,
                                                          const float* __restrict__ ar,
                                                          float* __restrict__ el,
                                                          float* __restrict__ er) {
    int idx = blockIdx.x * 256 + threadIdx.x;
    if (idx >= NR * NN * H) return;
    int r = idx / (NN * H);
    int w = idx - r * (NN * H);
    int h = w & (H - 1);
    const unsigned* fp = (const unsigned*)(featb + (size_t)r * NN * F + (size_t)w * D);
    const float4* ap = (const float4*)(al + r * F + h * D);
    const float4* bp = (const float4*)(ar + r * F + h * D);
    float sl = 0.f, sr = 0.f;
#pragma unroll
    for (int q = 0; q < D / 4; ++q) {
        unsigned u = fp[q];
        f32x2 d0 = fp8x2_to_f32((unsigned short)(u & 0xffff));
        f32x2 d1 = fp8x2_to_f32((unsigned short)(u >> 16));
        float4 a = ap[q], b = bp[q];
        sl += d0.x * a.x + d0.y * a.y + d1.x * a.z + d1.y * a.w;
        sr += d0.x * b.x + d0.y * b.y + d1.x * b.z + d1.y * b.w;
    }
    el[idx] = sl;
    er[idx] = sr;
}

// ---------------- wave-cooperative aggregation: half-wave per edge ----------
// Lane owns 4 consecutive features fi..fi+3 (one u32 fp8 load). The two
// 32-lane halves process different edges concurrently (half = lane>>5), so
// per 8-edge batch a lane issues only 4 gathers. Weights computed once per
// (edge,head) by producer lanes (slot = lane&(CH-1), head = lane>>4), shfl
// broadcast to consumers. Ends with cross-half reduce; half 0 writes float4.
template <int H, int FIN>
__global__ __launch_bounds__(256) void aggr3_kernel(const int* __restrict__ row_ptr,
                                                    const int* __restrict__ csr_src,
                                                    const float* __restrict__ el,
                                                    const float* __restrict__ er,
                                                    const unsigned char* __restrict__ featb,
                                                    const float* __restrict__ resid,
                                                    const float* __restrict__ bias,
                                                    float* __restrict__ outp) {
    const int gid = blockIdx.x * 256 + threadIdx.x;
    const int d = gid >> 6;
    const int lane = gid & 63;
    if (d >= NN) return;
    const int half = lane >> 5;
    const int fi = (lane & 31) * 4;                   // features [fi, fi+4)
    const int CH = (H == 4) ? 16 : 64;
    const int myh = (H == 4) ? (fi >> 5) : 0;         // consumer head
    const int ph = (H == 4) ? (lane >> 4) : 0;        // producer head
    const int sub = lane & (CH - 1);                  // producer edge slot
    const int grpbase = (H == 4) ? myh * 16 : 0;      // shfl source base
    float a0 = 0.f, a1 = 0.f, a2 = 0.f, a3 = 0.f;
    for (int r = 0; r < NR; ++r) {
        const int idx = r * NN + d;
        const int rs = row_ptr[idx];
        const int re = (idx + 1 < M3) ? row_ptr[idx + 1] : E3;
        const float erh = er[(size_t)r * NN * H + d * H + ph];
        const float* elr = el + (size_t)r * NN * H;
        const unsigned char* fb = featb + (size_t)r * NN * F;
        float den = 0.f, b0 = 0.f, b1 = 0.f, b2 = 0.f, b3 = 0.f;
        for (int base = rs; base < re; base += CH) {
            int cnt = re - base;
            if (cnt > CH) cnt = CH;
            int s_l = 0;
            float w_l = 0.f;
            if (sub < cnt) {
                s_l = csr_src[base + sub];
                w_l = __expf(lrelu(elr[s_l * H + ph] + erh));
            }
            den += w_l;
            for (int j = 0; j < cnt; j += 8) {        // 8 edges/batch: 4 per half
                int sj[4];
                float wj[4];
#pragma unroll
                for (int q = 0; q < 4; ++q) {
                    int e = j + 2 * q + half;
                    int ec = e < cnt ? e : cnt - 1;   // wave-uniform-bound clamp
                    sj[q] = __shfl(s_l, grpbase + ec);
                    float w = __shfl(w_l, grpbase + ec);
                    wj[q] = (e < cnt) ? w : 0.f;
                }
                unsigned u[4];
#pragma unroll
                for (int q = 0; q < 4; ++q)
                    u[q] = *(const unsigned*)(fb + (size_t)sj[q] * F + fi);
#pragma unroll
                for (int q = 0; q < 4; ++q) {
                    f32x2 d0 = fp8x2_to_f32((unsigned short)(u[q] & 0xffff));
                    f32x2 d1 = fp8x2_to_f32((unsigned short)(u[q] >> 16));
                    b0 += wj[q] * d0.x;
                    b1 += wj[q] * d0.y;
                    b2 += wj[q] * d1.x;
                    b3 += wj[q] * d1.y;
                }
            }
        }
#pragma unroll
        for (int off = CH >> 1; off; off >>= 1) den += __shfl_xor(den, off);
        float dh = (H == 4) ? __shfl(den, grpbase) : den;
        float rd = 1.f / fmaxf(dh, 1e-9f);
        a0 += b0 * rd;
        a1 += b1 * rd;
        a2 += b2 * rd;
        a3 += b3 * rd;
    }
    // combine the two halves' edge subsets
    a0 += __shfl_xor(a0, 32);
    a1 += __shfl_xor(a1, 32);
    a2 += __shfl_xor(a2, 32);
    a3 += __shfl_xor(a3, 32);
    if (half == 0) {
        const float third = 1.f / 3.f;
        size_t o = (size_t)d * F + fi;
        float4 bA = *(const float4*)&bias[fi];
        float4 bB = *(const float4*)&bias[F + fi];
        float4 bC = *(const float4*)&bias[2 * F + fi];
        float4 rv = *(const float4*)&resid[o];
        float v0 = a0 * third + rv.x + (bA.x + bB.x + bC.x) * third;
        float v1 = a1 * third + rv.y + (bA.y + bB.y + bC.y) * third;
        float v2 = a2 * third + rv.z + (bA.z + bB.z + bC.z) * third;
        float v3 = a3 * third + rv.w + (bA.w + bB.w + bC.w) * third;
        if (FIN == 1) {
            v0 = v0 > 0.f ? v0 : (__expf(v0) - 1.f);
            v1 = v1 > 0.f ? v1 : (__expf(v1) - 1.f);
            v2 = v2 > 0.f ? v2 : (__expf(v2) - 1.f);
            v3 = v3 > 0.f ? v3 : (__expf(v3) - 1.f);
        }
        *(float4*)&outp[o] = make_float4(v0, v1, v2, v3);
    }
}

extern "C" void kernel_launch(void* const* d_in, const int* in_sizes, int n_in,
                              void* d_out, int out_size, void* d_ws, size_t ws_size,
                              hipStream_t stream) {
    const float* x   = (const float*)d_in[0];
    const int* esrc  = (const int*)d_in[1];
    const int* edst  = (const int*)d_in[2];
    const float* W1  = (const float*)d_in[3];
    const float* b1  = (const float*)d_in[4];
    const float* al1 = (const float*)d_in[5];
    const float* ar1 = (const float*)d_in[6];
    const float* W2  = (const float*)d_in[7];
    const float* b2  = (const float*)d_in[8];
    const float* al2 = (const float*)d_in[9];
    const float* ar2 = (const float*)d_in[10];
    float* out = (float*)d_out;

    // workspace (~60 MB; proven-safe >= 108.8 MB). h1 lives in d_out.
    char* p = (char*)d_ws;
    unsigned char* featb = (unsigned char*)p;    p += (size_t)NR * NN * F;      // 38.4 MB
    float* el    = (float*)p;                    p += (size_t)NR * NN * 4 * 4;  // 4.8 MB
    float* er    = (float*)p;                    p += (size_t)NR * NN * 4 * 4;
    int* row_ptr = (int*)p;                      p += (size_t)M3 * 4;
    int* alloc   = (int*)p;                      p += (size_t)M3 * 4;
    int* bsum    = (int*)p;                      p += (size_t)((NB1 + 63) & ~63) * 4;
    int* csr_src = (int*)p;                      p += (size_t)E3 * 4;           // 9.6 MB
    unsigned short* Bpack = (unsigned short*)p;  p += (size_t)6 * F * F * 2;
    float* h1 = out;

    dim3 b256(256);
    const int eg3 = (E3 + 255) / 256;
    const int gemm_grid = (NN + 127) / 128;
    const int g3h4 = (NR * NN * 4 + 255) / 256;
    const int g3h1 = (NR * NN * 1 + 255) / 256;
    const int agg = (NN * 64 + 255) / 256;

    // ---- build CSR by dst (shared by both layers) + pack weights
    hipMemsetAsync(row_ptr, 0, (size_t)M3 * 4, stream);
    packW_kernel<<<(6 * F * F + 255) / 256, b256, 0, stream>>>(W1, W2, Bpack);
    hist_kernel<<<eg3, b256, 0, stream>>>(edst, row_ptr);
    scan1_kernel<<<NB1, b256, 0, stream>>>(row_ptr, bsum, M3);
    scan2_kernel<<<1, b256, 0, stream>>>(bsum, NB1);
    scan3_kernel<<<NB1, b256, 0, stream>>>(row_ptr, alloc, bsum, M3);
    for (int pass = 0; pass < NPASS; ++pass)
        scatter_pass_kernel<<<eg3, b256, 0, stream>>>(esrc, edst, alloc, csr_src, pass * PW);

    // ---- layer 1: GATConv(128 -> 32, 4 heads) x3 relations, mean, +res +bias, ELU
    gemm_fused_kernel<<<gemm_grid, b256, 0, stream>>>(x, Bpack, featb);
    el_er_fused_kernel<4, 32><<<g3h4, b256, 0, stream>>>(featb, al1, ar1, el, er);
    aggr3_kernel<4, 1><<<agg, b256, 0, stream>>>(row_ptr, csr_src, el, er, featb, x, b1, h1);

    // ---- layer 2: GATConv(128 -> 128, 1 head) x3 relations, mean, +res +bias
    gemm_fused_kernel<<<gemm_grid, b256, 0, stream>>>(h1, Bpack + (size_t)3 * F * F, featb);
    el_er_fused_kernel<1, 128><<<g3h1, b256, 0, stream>>>(featb, al2, ar2, el, er);
    aggr3_kernel<1, 2><<<agg, b256, 0, stream>>>(row_ptr, csr_src, el, er, featb, h1, b2, out);
}